// Round 8
// baseline (476.205 us; speedup 1.0000x reference)
//
#include <hip/hip_runtime.h>
#include <hip/hip_fp16.h>
#include <math.h>

// ---------------------------------------------------------------------------
// DevignLite: 3-layer GCN + mean/max pool + MLP head.  N=100000, E=1.6M,
// D=64, G=256.
// Round 8: XCD-affine slab-partitioned aggregate WITH fat loads.
//   xh stored slab-major: 4 slabs [c][N][16] fp16, 3.2MB each (fits one
//   XCD's 4MB L2; physically separate so lines aren't shared across slabs).
//   k_aggregate: chunk = blockIdx&3 -> block->XCD round-robin pins slab c
//   to XCDs {c, c+4}.  Wave = 4 nodes x 8 edge-slots x 2 offsets; gathers
//   are dwordx4 (1KB/instr); per-lane loop bounds (exec mask) avoid
//   wave-max divergence waste; 24-shfl epilogue.
// Evidence: r5/r6/r7 FETCH pinned at 158-160MB (L2 capacity misses), dur
// tracks FETCH at ~2.8-3.4TB/s = XCD L2-fill path.  r4 proved %-slab
// partitioning cuts FETCH to 42MB; its failure was 4B-thin loads (fixed).
// ---------------------------------------------------------------------------

#define BKT_LOG 9
#define BKT (1 << BKT_LOG)   // 512 nodes per coarse bucket
#define CHUNK 2048           // edges per k_part block (8 per thread)

typedef float v2f __attribute__((ext_vector_type(2)));

// coarse histogram of dst >> BKT_LOG
__global__ __launch_bounds__(256) void k_chist(const int* __restrict__ dst,
                                               int* __restrict__ chist, int E, int B) {
  __shared__ int h[256];
  h[threadIdx.x] = 0;
  __syncthreads();
  for (long e = (long)blockIdx.x * blockDim.x + threadIdx.x; e < E;
       e += (long)gridDim.x * blockDim.x)
    atomicAdd(&h[dst[e] >> BKT_LOG], 1);
  __syncthreads();
  if (threadIdx.x < B && h[threadIdx.x]) atomicAdd(&chist[threadIdx.x], h[threadIdx.x]);
}

// exclusive scan of chist[B] -> cbase[B+1]; cursor copy -> gcur
__global__ __launch_bounds__(256) void k_cscan(const int* __restrict__ chist,
                                               int* __restrict__ cbase,
                                               int* __restrict__ gcur, int E, int B) {
  __shared__ int s[256];
  int v = (threadIdx.x < B) ? chist[threadIdx.x] : 0;
  s[threadIdx.x] = v;
  __syncthreads();
  for (int d = 1; d < 256; d <<= 1) {
    int t = (threadIdx.x >= (unsigned)d) ? s[threadIdx.x - d] : 0;
    __syncthreads();
    s[threadIdx.x] += t;
    __syncthreads();
  }
  if (threadIdx.x < B) {
    int ex = s[threadIdx.x] - v;
    cbase[threadIdx.x] = ex;
    gcur[threadIdx.x] = ex;
  }
  if (threadIdx.x == B) cbase[B] = E;
}

// partition pass: scatter (src,dst) pairs into coarse-bucket order.
// Block-exclusive contiguous slices -> single writer per cache line.
__global__ __launch_bounds__(256) void k_part(const int* __restrict__ src,
                                              const int* __restrict__ dst,
                                              int* __restrict__ gcur,
                                              int2* __restrict__ ebuf, int E, int B) {
  __shared__ int h[256], base[256], cur[256];
  long c0 = (long)blockIdx.x * CHUNK;
  int m = (int)min((long)CHUNK, (long)E - c0);
  int sreg[8], dreg[8];
  h[threadIdx.x] = 0;
  __syncthreads();
#pragma unroll
  for (int j = 0; j < 8; j++) {
    int idx = threadIdx.x + j * 256;
    if (idx < m) {
      sreg[j] = src[c0 + idx];
      dreg[j] = dst[c0 + idx];
      atomicAdd(&h[dreg[j] >> BKT_LOG], 1);
    }
  }
  __syncthreads();
  if (threadIdx.x < B && h[threadIdx.x])
    base[threadIdx.x] = atomicAdd(&gcur[threadIdx.x], h[threadIdx.x]);
  cur[threadIdx.x] = 0;
  __syncthreads();
#pragma unroll
  for (int j = 0; j < 8; j++) {
    int idx = threadIdx.x + j * 256;
    if (idx < m) {
      int k = dreg[j] >> BKT_LOG;
      int p = base[k] + atomicAdd(&cur[k], 1);
      ebuf[p] = make_int2(sreg[j], dreg[j]);
    }
  }
}

// per-bucket: node histogram + scan in LDS -> off/dinv, then place csrc.
__global__ __launch_bounds__(512) void k_bplace(const int2* __restrict__ ebuf,
                                                const int* __restrict__ cbase,
                                                int* __restrict__ off,
                                                int* __restrict__ csrc,
                                                float* __restrict__ dinv,
                                                int N, int E) {
  __shared__ int s[512];
  __shared__ int cur[512];
  int b = blockIdx.x, tid = threadIdx.x;
  int n0 = b << BKT_LOG;
  int nn = min(BKT, N - n0);
  int e0 = cbase[b], e1 = cbase[b + 1];
  s[tid] = 0;
  __syncthreads();
  for (int e = e0 + tid; e < e1; e += 512) atomicAdd(&s[ebuf[e].y - n0], 1);
  __syncthreads();
  int deg = s[tid];
  for (int d = 1; d < 512; d <<= 1) {
    int t = (tid >= d) ? s[tid - d] : 0;
    __syncthreads();
    s[tid] += t;
    __syncthreads();
  }
  int excl = s[tid] - deg;
  if (tid < nn) {
    off[n0 + tid] = e0 + excl;
    dinv[n0 + tid] = 1.0f / sqrtf((float)(1 + deg));
  }
  cur[tid] = excl;
  __syncthreads();
  for (int e = e0 + tid; e < e1; e += 512) {
    int2 p = ebuf[e];
    int pos = e0 + atomicAdd(&cur[p.y - n0], 1);
    csrc[pos] = p.x;
  }
  if (b == 0 && tid == 0) off[N] = E;
}

// ---------------------------------------------------------------------------
// Matmul, lane = row.  xw_h = act(xin) @ W * (256*dinv[row]) as fp16,
// written SLAB-MAJOR: slab c = feats [16c,16c+16) at xh4[c*2N + row*2 + o].
// W via wave-uniform broadcast loads; 32 packed-f32 accumulators per lane.
// ---------------------------------------------------------------------------
template <bool EMB, bool ACT>
__global__ __launch_bounds__(256) void k_matmul(const float* __restrict__ xin,
                                                const int* __restrict__ tok,
                                                const float* __restrict__ emb,
                                                const float* __restrict__ W,
                                                const float* __restrict__ bprev,
                                                const float* __restrict__ dinv,
                                                __half2* __restrict__ xwh, int n) {
  long row = (long)blockIdx.x * 256 + threadIdx.x;
  if (row >= n) return;
  const float4* W4 = (const float4*)W;
  const float4* b4 = (const float4*)bprev;
  const float4* xr;
  if (EMB) xr = (const float4*)(emb + (size_t)tok[row] * 64);
  else     xr = (const float4*)(xin + (size_t)row * 64);
  v2f acc[32];
#pragma unroll
  for (int i = 0; i < 32; i++) acc[i] = (v2f)(0.f);

  for (int d4 = 0; d4 < 16; d4++) {
    float4 xv = xr[d4];
    if (ACT) {
      float4 bb = b4[d4];
      xv.x = fmaxf(xv.x + bb.x, 0.f);
      xv.y = fmaxf(xv.y + bb.y, 0.f);
      xv.z = fmaxf(xv.z + bb.z, 0.f);
      xv.w = fmaxf(xv.w + bb.w, 0.f);
    }
    const float xs[4] = {xv.x, xv.y, xv.z, xv.w};
#pragma unroll
    for (int r = 0; r < 4; r++) {
      const float4* wr = W4 + (size_t)(d4 * 4 + r) * 16;   // uniform address
      v2f x2 = {xs[r], xs[r]};
#pragma unroll
      for (int cb = 0; cb < 16; cb++) {
        float4 w = wr[cb];
        v2f w0 = {w.x, w.y}, w1 = {w.z, w.w};
        acc[cb * 2 + 0] = __builtin_elementwise_fma(x2, w0, acc[cb * 2 + 0]);
        acc[cb * 2 + 1] = __builtin_elementwise_fma(x2, w1, acc[cb * 2 + 1]);
      }
    }
  }
  float di = dinv[row] * 256.0f;       // fp16-range scale, undone in aggregate
  __half2 hh[32];
#pragma unroll
  for (int c = 0; c < 32; c++)
    hh[c] = __float22half2_rn(make_float2(acc[c].x * di, acc[c].y * di));
  const uint4* src = (const uint4*)hh;   // chunk k = feats [8k, 8k+8)
  uint4* dst = (uint4*)xwh;              // slab-major
#pragma unroll
  for (int c = 0; c < 4; c++) {
    dst[(size_t)c * n * 2 + row * 2 + 0] = src[2 * c + 0];
    dst[(size_t)c * n * 2 + row * 2 + 1] = src[2 * c + 1];
  }
}

// ---------------------------------------------------------------------------
// Aggregate, slab-parallel, XCD-affine.  chunk c = blockIdx&3; wave = 4
// nodes; lane = (n4: bits4-5, g: bits1-3, o: bit0).  Per node: 8 edge slots
// x 2x16B offsets; one dwordx4 = 1KB covering 4 nodes x 8 edges' 32B
// quarter-rows.  Per-lane loop bounds; xor-reduce over g (24 shfl).
// agg[t][16c..16c+16) = (dinv[t]/256) * (xh_c[t] + sum_in xh_c[s])
// ---------------------------------------------------------------------------
__global__ __launch_bounds__(256) void k_aggregate(const int* __restrict__ off,
                                                   const int* __restrict__ csrc,
                                                   const float* __restrict__ dinv,
                                                   const __half2* __restrict__ xh,
                                                   float* __restrict__ agg, int n) {
  int c = blockIdx.x & 3;
  int lane = threadIdx.x & 63;
  int n4 = lane >> 4, g = (lane >> 1) & 7, o = lane & 1;
  int t = (blockIdx.x >> 2) * 16 + (threadIdx.x >> 6) * 4 + n4;
  bool valid = t < n;
  int tc = valid ? t : n - 1;
  int e0 = off[tc], e1 = off[tc + 1];
  if (!valid) e1 = e0;
  const uint4* x4 = (const uint4*)xh;
  const size_t cb = (size_t)c * n * 2;

  float acc[8];
  if (g == 0) {  // self term, once per (node, o)
    uint4 v = x4[cb + (size_t)tc * 2 + o];
    const __half2* hv = (const __half2*)&v;
#pragma unroll
    for (int k = 0; k < 4; k++) {
      float2 f = __half22float2(hv[k]);
      acc[2 * k] = f.x;
      acc[2 * k + 1] = f.y;
    }
  } else {
#pragma unroll
    for (int k = 0; k < 8; k++) acc[k] = 0.f;
  }

  for (int it = e0 + g; __ballot(it < e1) != 0ull; it += 8) {
    if (it < e1) {
      int s = csrc[it];
      uint4 v = x4[cb + (size_t)s * 2 + o];
      const __half2* hv = (const __half2*)&v;
#pragma unroll
      for (int k = 0; k < 4; k++) {
        float2 f = __half22float2(hv[k]);
        acc[2 * k] += f.x;
        acc[2 * k + 1] += f.y;
      }
    }
  }

  // reduce over g (lane bits 1-3)
#pragma unroll
  for (int m = 2; m <= 8; m <<= 1) {
#pragma unroll
    for (int k = 0; k < 8; k++) acc[k] += __shfl_xor(acc[k], m);
  }

  if (valid && g == 0) {
    float sc = dinv[t] * (1.0f / 256.0f);
    float4* p = (float4*)(agg + (size_t)t * 64 + c * 16 + o * 8);
    p[0] = make_float4(acc[0] * sc, acc[1] * sc, acc[2] * sc, acc[3] * sc);
    p[1] = make_float4(acc[4] * sc, acc[5] * sc, acc[6] * sc, acc[7] * sc);
  }
}

// batch is sorted: per-wave register segment reduction, flush on boundary.
__global__ __launch_bounds__(256) void k_pool(const float* __restrict__ x,
                                              const float* __restrict__ b,
                                              const int* __restrict__ batch,
                                              float* __restrict__ hsum,
                                              float* __restrict__ hmax,
                                              int* __restrict__ cntg, int n) {
  int wid = (blockIdx.x * blockDim.x + threadIdx.x) >> 6;
  int lane = threadIdx.x & 63;
  int i0 = wid * 64;
  if (i0 >= n) return;
  int i1 = min(i0 + 64, n);
  float bb = b[lane];
  int batch_l = (i0 + lane < n) ? batch[i0 + lane] : 0;
  float gsum = 0.f, gmax = 0.f;
  int cur = __shfl(batch_l, 0);
  int c = 0;
  for (int i = i0; i < i1; i++) {
    int g = __shfl(batch_l, i - i0);
    if (g != cur) {
      atomicAdd(&hsum[cur * 64 + lane], gsum);
      atomicMax((int*)&hmax[cur * 64 + lane], __float_as_int(gmax));
      if (lane == 0) atomicAdd(&cntg[cur], c);
      gsum = 0.f; gmax = 0.f; c = 0; cur = g;
    }
    float v = fmaxf(x[(long)i * 64 + lane] + bb, 0.0f);
    gsum += v;
    gmax = fmaxf(gmax, v);
    c++;
  }
  atomicAdd(&hsum[cur * 64 + lane], gsum);
  atomicMax((int*)&hmax[cur * 64 + lane], __float_as_int(gmax));
  if (lane == 0) atomicAdd(&cntg[cur], c);
}

// one block (64 threads) per graph: logits = relu(h@Wc1+bc1)@Wc2+bc2
__global__ __launch_bounds__(64) void k_cls(const float* __restrict__ hsum,
                                            const float* __restrict__ hmax,
                                            const int* __restrict__ cnt,
                                            const float* __restrict__ Wc1,
                                            const float* __restrict__ bc1,
                                            const float* __restrict__ Wc2,
                                            const float* __restrict__ bc2,
                                            float* __restrict__ out) {
  __shared__ float h[128];
  __shared__ float hid[64];
  int g = blockIdx.x, j = threadIdx.x;
  int c = cnt[g];
  float cf = (float)(c > 0 ? c : 1);
  h[j] = hsum[g * 64 + j] / cf;
  h[64 + j] = hmax[g * 64 + j];
  __syncthreads();
  float acc = bc1[j];
  for (int k = 0; k < 128; k++) acc += h[k] * Wc1[k * 64 + j];
  hid[j] = fmaxf(acc, 0.f);
  __syncthreads();
  if (j < 2) {
    float a = bc2[j];
    for (int k = 0; k < 64; k++) a += hid[k] * Wc2[k * 2 + j];
    out[g * 2 + j] = a;
  }
}

extern "C" void kernel_launch(void* const* d_in, const int* in_sizes, int n_in,
                              void* d_out, int out_size, void* d_ws, size_t ws_size,
                              hipStream_t stream) {
  const int N = in_sizes[0];
  const int E = in_sizes[1] / 2;
  const int G = out_size / 2;
  const int B = (N + BKT - 1) >> BKT_LOG;

  const int* tok   = (const int*)d_in[0];
  const int* ei    = (const int*)d_in[1];
  const int* batch = (const int*)d_in[2];
  const float* emb = (const float*)d_in[3];
  const float* W0 = (const float*)d_in[4];  const float* b0 = (const float*)d_in[5];
  const float* W1 = (const float*)d_in[6];  const float* b1 = (const float*)d_in[7];
  const float* W2 = (const float*)d_in[8];  const float* b2 = (const float*)d_in[9];
  const float* Wc1 = (const float*)d_in[10]; const float* bc1 = (const float*)d_in[11];
  const float* Wc2 = (const float*)d_in[12]; const float* bc2 = (const float*)d_in[13];
  const int* srcp = ei;
  const int* dstp = ei + E;

  // ---- workspace carve-up (4-byte units) ----
  int* off    = (int*)d_ws;                      // N+2
  int* csrc   = off + N + 2;                     // E
  float* dinv = (float*)(csrc + E);              // N
  int* chist  = (int*)(dinv + N);                // 256
  int* cbase  = chist + 256;                     // 256 (B+1 used)
  int* gcur   = cbase + 256;                     // 256
  __half2* xh = (__half2*)(gcur + 256);          // 4 slabs x N x 16 half (12.8 MB)
  float* bufA = (float*)((int*)(gcur + 256) + (size_t)N * 32);  // N*64 fp32
  float* bufB = bufA + (size_t)N * 64;           // N*64 fp32
  int2* ebuf  = (int2*)bufA;                     // E pairs (dead before agg0)
  float* hsum = bufB + (size_t)N * 64;           // G*64
  float* hmax = hsum + (size_t)G * 64;           // G*64
  int*   cntg = (int*)(hmax + (size_t)G * 64);   // G

  auto cdiv = [](long a, long b) { return (int)((a + b - 1) / b); };
  const int aggBlocks = 4 * cdiv(N, 16);   // blockIdx&3 = slab -> XCD affine

  // ---- CSR build (single-writer placement) ----
  hipMemsetAsync(chist, 0, 256 * sizeof(int), stream);
  k_chist<<<cdiv(E, CHUNK), 256, 0, stream>>>(dstp, chist, E, B);
  k_cscan<<<1, 256, 0, stream>>>(chist, cbase, gcur, E, B);
  k_part<<<cdiv(E, CHUNK), 256, 0, stream>>>(srcp, dstp, gcur, ebuf, E, B);
  k_bplace<<<B, 512, 0, stream>>>(ebuf, cbase, off, csrc, dinv, N, E);

  // ---- 3 GCN layers ----
  k_matmul<true, false><<<cdiv(N, 256), 256, 0, stream>>>(nullptr, tok, emb, W0, nullptr, dinv, xh, N);
  k_aggregate<<<aggBlocks, 256, 0, stream>>>(off, csrc, dinv, xh, bufA, N);

  k_matmul<false, true><<<cdiv(N, 256), 256, 0, stream>>>(bufA, nullptr, nullptr, W1, b0, dinv, xh, N);
  k_aggregate<<<aggBlocks, 256, 0, stream>>>(off, csrc, dinv, xh, bufB, N);

  k_matmul<false, true><<<cdiv(N, 256), 256, 0, stream>>>(bufB, nullptr, nullptr, W2, b1, dinv, xh, N);
  k_aggregate<<<aggBlocks, 256, 0, stream>>>(off, csrc, dinv, xh, bufA, N);

  // ---- pooling (relu+b2 fused) ----
  hipMemsetAsync(hsum, 0, (size_t)G * 129 * sizeof(float), stream);
  k_pool<<<cdiv(N, 256), 256, 0, stream>>>(bufA, b2, batch, hsum, hmax, cntg, N);

  // ---- classifier head ----
  k_cls<<<G, 64, 0, stream>>>(hsum, hmax, cntg, Wc1, bc1, Wc2, bc2, (float*)d_out);
}

// Round 9
// 467.657 us; speedup vs baseline: 1.0183x; 1.0183x over previous
//
#include <hip/hip_runtime.h>
#include <hip/hip_fp16.h>
#include <math.h>

// ---------------------------------------------------------------------------
// DevignLite: 3-layer GCN + mean/max pool + MLP head.  N=100000, E=1.6M,
// D=64, G=256.
// Round 9:
//  - Aggregate: keeps r8's XCD-affine slab layout (FETCH 160->53MB proven)
//    but inner loop uses v_dot2_f32_f16 (fdot2 w/ (1,0)/(0,1) masks) =
//    convert+accumulate in 1 instr; branchless validity by zeroed masks;
//    wave-max loop bound; unroll x2 (two 1KB gathers in flight).
//  - fp16 inter-layer activations y = 4096*relu(conv+b) (layers 0,1):
//    aggregate epilogue folds bias+relu+scale; matmul reads fp16 rows
//    (half traffic, no ACT pass), compensates with dinv/16 output scale.
//    Final layer stays fp32 -> pool unchanged.
//  - ebuf packed to 1 int: (dst&511)<<17 | src (26 bits).
// ---------------------------------------------------------------------------

#define BKT_LOG 9
#define BKT (1 << BKT_LOG)   // 512 nodes per coarse bucket
#define CHUNK 2048           // edges per k_part block (8 per thread)

typedef float v2f __attribute__((ext_vector_type(2)));
typedef _Float16 h2 __attribute__((ext_vector_type(2)));

union HU { unsigned u; h2 h; };
__device__ inline h2 h2bits(unsigned u) { HU x; x.u = u; return x.h; }

#if __has_builtin(__builtin_amdgcn_fdot2)
#define FDOT2(a, b, c) __builtin_amdgcn_fdot2((a), (b), (c), false)
#else
__device__ inline float FDOT2(h2 a, h2 b, float c) {
  return (float)a.x * (float)b.x + (float)a.y * (float)b.y + c;
}
#endif

#define MASK_X 0x00003C00u   // half2 (1,0)
#define MASK_Y 0x3C000000u   // half2 (0,1)

// acc[0..7] += masked convert of 8 halfs in v
__device__ inline void acc8(const uint4& v, unsigned m0, unsigned m1, float* acc) {
  const unsigned* w = (const unsigned*)&v;
#pragma unroll
  for (int k = 0; k < 4; k++) {
    h2 hv = h2bits(w[k]);
    acc[2 * k]     = FDOT2(hv, h2bits(m0), acc[2 * k]);
    acc[2 * k + 1] = FDOT2(hv, h2bits(m1), acc[2 * k + 1]);
  }
}

// coarse histogram of dst >> BKT_LOG
__global__ __launch_bounds__(256) void k_chist(const int* __restrict__ dst,
                                               int* __restrict__ chist, int E, int B) {
  __shared__ int h[256];
  h[threadIdx.x] = 0;
  __syncthreads();
  for (long e = (long)blockIdx.x * blockDim.x + threadIdx.x; e < E;
       e += (long)gridDim.x * blockDim.x)
    atomicAdd(&h[dst[e] >> BKT_LOG], 1);
  __syncthreads();
  if (threadIdx.x < B && h[threadIdx.x]) atomicAdd(&chist[threadIdx.x], h[threadIdx.x]);
}

// exclusive scan of chist[B] -> cbase[B+1]; cursor copy -> gcur
__global__ __launch_bounds__(256) void k_cscan(const int* __restrict__ chist,
                                               int* __restrict__ cbase,
                                               int* __restrict__ gcur, int E, int B) {
  __shared__ int s[256];
  int v = (threadIdx.x < B) ? chist[threadIdx.x] : 0;
  s[threadIdx.x] = v;
  __syncthreads();
  for (int d = 1; d < 256; d <<= 1) {
    int t = (threadIdx.x >= (unsigned)d) ? s[threadIdx.x - d] : 0;
    __syncthreads();
    s[threadIdx.x] += t;
    __syncthreads();
  }
  if (threadIdx.x < B) {
    int ex = s[threadIdx.x] - v;
    cbase[threadIdx.x] = ex;
    gcur[threadIdx.x] = ex;
  }
  if (threadIdx.x == B) cbase[B] = E;
}

// partition: scatter packed (local_dst<<17 | src) into coarse-bucket order.
__global__ __launch_bounds__(256) void k_part(const int* __restrict__ src,
                                              const int* __restrict__ dst,
                                              int* __restrict__ gcur,
                                              int* __restrict__ ebuf, int E, int B) {
  __shared__ int h[256], base[256], cur[256];
  long c0 = (long)blockIdx.x * CHUNK;
  int m = (int)min((long)CHUNK, (long)E - c0);
  int preg[8], kreg[8];
  h[threadIdx.x] = 0;
  __syncthreads();
#pragma unroll
  for (int j = 0; j < 8; j++) {
    int idx = threadIdx.x + j * 256;
    if (idx < m) {
      int s = src[c0 + idx];
      int d = dst[c0 + idx];
      preg[j] = ((d & (BKT - 1)) << 17) | s;
      kreg[j] = d >> BKT_LOG;
      atomicAdd(&h[kreg[j]], 1);
    }
  }
  __syncthreads();
  if (threadIdx.x < B && h[threadIdx.x])
    base[threadIdx.x] = atomicAdd(&gcur[threadIdx.x], h[threadIdx.x]);
  cur[threadIdx.x] = 0;
  __syncthreads();
#pragma unroll
  for (int j = 0; j < 8; j++) {
    int idx = threadIdx.x + j * 256;
    if (idx < m) {
      int k = kreg[j];
      int p = base[k] + atomicAdd(&cur[k], 1);
      ebuf[p] = preg[j];
    }
  }
}

// per-bucket: node histogram + scan in LDS -> off/dinv, then place csrc.
__global__ __launch_bounds__(512) void k_bplace(const int* __restrict__ ebuf,
                                                const int* __restrict__ cbase,
                                                int* __restrict__ off,
                                                int* __restrict__ csrc,
                                                float* __restrict__ dinv,
                                                int N, int E) {
  __shared__ int s[512];
  __shared__ int cur[512];
  int b = blockIdx.x, tid = threadIdx.x;
  int n0 = b << BKT_LOG;
  int nn = min(BKT, N - n0);
  int e0 = cbase[b], e1 = cbase[b + 1];
  s[tid] = 0;
  __syncthreads();
  for (int e = e0 + tid; e < e1; e += 512) atomicAdd(&s[ebuf[e] >> 17], 1);
  __syncthreads();
  int deg = s[tid];
  for (int d = 1; d < 512; d <<= 1) {
    int t = (tid >= d) ? s[tid - d] : 0;
    __syncthreads();
    s[tid] += t;
    __syncthreads();
  }
  int excl = s[tid] - deg;
  if (tid < nn) {
    off[n0 + tid] = e0 + excl;
    dinv[n0 + tid] = 1.0f / sqrtf((float)(1 + deg));
  }
  cur[tid] = excl;
  __syncthreads();
  for (int e = e0 + tid; e < e1; e += 512) {
    int p = ebuf[e];
    int pos = e0 + atomicAdd(&cur[p >> 17], 1);
    csrc[pos] = p & 0x1FFFF;
  }
  if (b == 0 && tid == 0) off[N] = E;
}

// ---------------------------------------------------------------------------
// Matmul, lane = row.  EMB: input = emb_table[tok[row]] (fp32).
// else: input = y fp16 rows (pre-relu'ed, pre-biased, x4096 scale).
// Output xh slab-major fp16, scaled by dinv*(256 or 1/16).
// ---------------------------------------------------------------------------
template <bool EMB>
__global__ __launch_bounds__(256) void k_matmul(const void* __restrict__ xin,
                                                const int* __restrict__ tok,
                                                const float* __restrict__ emb,
                                                const float* __restrict__ W,
                                                const float* __restrict__ dinv,
                                                __half2* __restrict__ xwh, int n) {
  long row = (long)blockIdx.x * 256 + threadIdx.x;
  if (row >= n) return;
  const float4* W4 = (const float4*)W;
  v2f acc[32];
#pragma unroll
  for (int i = 0; i < 32; i++) acc[i] = (v2f)(0.f);

  if (EMB) {
    const float4* xr = (const float4*)(emb + (size_t)tok[row] * 64);
    for (int d4 = 0; d4 < 16; d4++) {
      float4 xv = xr[d4];
      const float xs[4] = {xv.x, xv.y, xv.z, xv.w};
#pragma unroll
      for (int r = 0; r < 4; r++) {
        const float4* wr = W4 + (size_t)(d4 * 4 + r) * 16;   // uniform
        v2f x2 = {xs[r], xs[r]};
#pragma unroll
        for (int cb = 0; cb < 16; cb++) {
          float4 w = wr[cb];
          v2f w0 = {w.x, w.y}, w1 = {w.z, w.w};
          acc[cb * 2 + 0] = __builtin_elementwise_fma(x2, w0, acc[cb * 2 + 0]);
          acc[cb * 2 + 1] = __builtin_elementwise_fma(x2, w1, acc[cb * 2 + 1]);
        }
      }
    }
  } else {
    const uint4* xr = (const uint4*)((const __half*)xin + (size_t)row * 64);
    for (int k8 = 0; k8 < 8; k8++) {
      uint4 v = xr[k8];
      const unsigned* wv = (const unsigned*)&v;
      float xs[8];
#pragma unroll
      for (int k = 0; k < 4; k++) {
        h2 hh = h2bits(wv[k]);
        xs[2 * k] = (float)hh.x;
        xs[2 * k + 1] = (float)hh.y;
      }
#pragma unroll
      for (int r = 0; r < 8; r++) {
        const float4* wr = W4 + (size_t)(k8 * 8 + r) * 16;   // uniform
        v2f x2 = {xs[r], xs[r]};
#pragma unroll
        for (int cb = 0; cb < 16; cb++) {
          float4 w = wr[cb];
          v2f w0 = {w.x, w.y}, w1 = {w.z, w.w};
          acc[cb * 2 + 0] = __builtin_elementwise_fma(x2, w0, acc[cb * 2 + 0]);
          acc[cb * 2 + 1] = __builtin_elementwise_fma(x2, w1, acc[cb * 2 + 1]);
        }
      }
    }
  }
  float di = dinv[row] * (EMB ? 256.0f : (1.0f / 16.0f));
  __half2 hh[32];
#pragma unroll
  for (int c = 0; c < 32; c++)
    hh[c] = __float22half2_rn(make_float2(acc[c].x * di, acc[c].y * di));
  const uint4* src = (const uint4*)hh;   // chunk k = feats [8k, 8k+8)
  uint4* dst = (uint4*)xwh;              // slab-major
#pragma unroll
  for (int c = 0; c < 4; c++) {
    dst[(size_t)c * n * 2 + row * 2 + 0] = src[2 * c + 0];
    dst[(size_t)c * n * 2 + row * 2 + 1] = src[2 * c + 1];
  }
}

// ---------------------------------------------------------------------------
// Aggregate, slab-parallel, XCD-affine, fdot2 inner loop.
// chunk c = blockIdx&3; wave = 4 nodes; lane = (n4:bits4-5, g:bits1-3, o:bit0).
// FOLD: out = fp16  4096*relu(conv + bias)  (row-major [n][64])
// PLAIN: out = fp32 conv                    (row-major [n][64])
// where conv = (dinv[t]/256) * (xh_c[t] + sum_in xh_c[s]).
// ---------------------------------------------------------------------------
template <bool FOLD>
__global__ __launch_bounds__(256) void k_aggregate(const int* __restrict__ off,
                                                   const int* __restrict__ csrc,
                                                   const float* __restrict__ dinv,
                                                   const __half* __restrict__ xh,
                                                   const float* __restrict__ bias,
                                                   void* __restrict__ outp, int n) {
  int c = blockIdx.x & 3;
  int lane = threadIdx.x & 63;
  int n4 = lane >> 4, g = (lane >> 1) & 7, o = lane & 1;
  int t = (blockIdx.x >> 2) * 16 + (threadIdx.x >> 6) * 4 + n4;
  bool valid = t < n;
  int tc = valid ? t : n - 1;
  int e0 = off[tc], e1 = off[tc + 1];
  if (!valid) e1 = e0;
  const uint4* x4 = (const uint4*)xh + (size_t)c * n * 2;   // 32B rows

  float acc[8];
#pragma unroll
  for (int k = 0; k < 8; k++) acc[k] = 0.f;
  {  // self term (g==0 lanes only; branchless via mask)
    uint4 v = x4[(size_t)tc * 2 + o];
    unsigned m0 = (g == 0) ? MASK_X : 0u, m1 = (g == 0) ? MASK_Y : 0u;
    acc8(v, m0, m1, acc);
  }

  // wave-max degree over the 4 node-subgroups (lane bits 4,5)
  int mxd = e1 - e0;
  mxd = max(mxd, __shfl_xor(mxd, 16));
  mxd = max(mxd, __shfl_xor(mxd, 32));

  int it = e0 + g;
  for (int r = 0; r < mxd; r += 16) {
    int i0 = it, i1 = it + 8;
    it += 16;
    bool a0 = i0 < e1, a1 = i1 < e1;
    int s0 = 0, s1 = 0;
    if (a0) s0 = csrc[i0];
    if (a1) s1 = csrc[i1];
    uint4 v0 = x4[(size_t)s0 * 2 + o];
    uint4 v1 = x4[(size_t)s1 * 2 + o];
    acc8(v0, a0 ? MASK_X : 0u, a0 ? MASK_Y : 0u, acc);
    acc8(v1, a1 ? MASK_X : 0u, a1 ? MASK_Y : 0u, acc);
  }

  // reduce over g (lane bits 1-3)
#pragma unroll
  for (int m = 2; m <= 8; m <<= 1) {
#pragma unroll
    for (int k = 0; k < 8; k++) acc[k] += __shfl_xor(acc[k], m);
  }

  if (valid && g == 0) {
    float sc = dinv[t] * (1.0f / 256.0f);
    int f0 = c * 16 + o * 8;
    if (FOLD) {
      float4 bb0 = *(const float4*)(bias + f0);
      float4 bb1 = *(const float4*)(bias + f0 + 4);
      const float bs[8] = {bb0.x, bb0.y, bb0.z, bb0.w, bb1.x, bb1.y, bb1.z, bb1.w};
      __half2 hh[4];
#pragma unroll
      for (int k = 0; k < 4; k++) {
        float u0 = fmaxf(acc[2 * k] * sc + bs[2 * k], 0.f) * 4096.f;
        float u1 = fmaxf(acc[2 * k + 1] * sc + bs[2 * k + 1], 0.f) * 4096.f;
        hh[k] = __float22half2_rn(make_float2(u0, u1));
      }
      *(uint4*)((__half*)outp + (size_t)t * 64 + f0) = *(const uint4*)hh;
    } else {
      float4* p = (float4*)((float*)outp + (size_t)t * 64 + f0);
      p[0] = make_float4(acc[0] * sc, acc[1] * sc, acc[2] * sc, acc[3] * sc);
      p[1] = make_float4(acc[4] * sc, acc[5] * sc, acc[6] * sc, acc[7] * sc);
    }
  }
}

// batch is sorted: per-wave register segment reduction, flush on boundary.
__global__ __launch_bounds__(256) void k_pool(const float* __restrict__ x,
                                              const float* __restrict__ b,
                                              const int* __restrict__ batch,
                                              float* __restrict__ hsum,
                                              float* __restrict__ hmax,
                                              int* __restrict__ cntg, int n) {
  int wid = (blockIdx.x * blockDim.x + threadIdx.x) >> 6;
  int lane = threadIdx.x & 63;
  int i0 = wid * 64;
  if (i0 >= n) return;
  int i1 = min(i0 + 64, n);
  float bb = b[lane];
  int batch_l = (i0 + lane < n) ? batch[i0 + lane] : 0;
  float gsum = 0.f, gmax = 0.f;
  int cur = __shfl(batch_l, 0);
  int c = 0;
  for (int i = i0; i < i1; i++) {
    int g = __shfl(batch_l, i - i0);
    if (g != cur) {
      atomicAdd(&hsum[cur * 64 + lane], gsum);
      atomicMax((int*)&hmax[cur * 64 + lane], __float_as_int(gmax));
      if (lane == 0) atomicAdd(&cntg[cur], c);
      gsum = 0.f; gmax = 0.f; c = 0; cur = g;
    }
    float v = fmaxf(x[(long)i * 64 + lane] + bb, 0.0f);
    gsum += v;
    gmax = fmaxf(gmax, v);
    c++;
  }
  atomicAdd(&hsum[cur * 64 + lane], gsum);
  atomicMax((int*)&hmax[cur * 64 + lane], __float_as_int(gmax));
  if (lane == 0) atomicAdd(&cntg[cur], c);
}

// one block (64 threads) per graph: logits = relu(h@Wc1+bc1)@Wc2+bc2
__global__ __launch_bounds__(64) void k_cls(const float* __restrict__ hsum,
                                            const float* __restrict__ hmax,
                                            const int* __restrict__ cnt,
                                            const float* __restrict__ Wc1,
                                            const float* __restrict__ bc1,
                                            const float* __restrict__ Wc2,
                                            const float* __restrict__ bc2,
                                            float* __restrict__ out) {
  __shared__ float h[128];
  __shared__ float hid[64];
  int g = blockIdx.x, j = threadIdx.x;
  int c = cnt[g];
  float cf = (float)(c > 0 ? c : 1);
  h[j] = hsum[g * 64 + j] / cf;
  h[64 + j] = hmax[g * 64 + j];
  __syncthreads();
  float acc = bc1[j];
  for (int k = 0; k < 128; k++) acc += h[k] * Wc1[k * 64 + j];
  hid[j] = fmaxf(acc, 0.f);
  __syncthreads();
  if (j < 2) {
    float a = bc2[j];
    for (int k = 0; k < 64; k++) a += hid[k] * Wc2[k * 2 + j];
    out[g * 2 + j] = a;
  }
}

extern "C" void kernel_launch(void* const* d_in, const int* in_sizes, int n_in,
                              void* d_out, int out_size, void* d_ws, size_t ws_size,
                              hipStream_t stream) {
  const int N = in_sizes[0];
  const int E = in_sizes[1] / 2;
  const int G = out_size / 2;
  const int B = (N + BKT - 1) >> BKT_LOG;

  const int* tok   = (const int*)d_in[0];
  const int* ei    = (const int*)d_in[1];
  const int* batch = (const int*)d_in[2];
  const float* emb = (const float*)d_in[3];
  const float* W0 = (const float*)d_in[4];  const float* b0 = (const float*)d_in[5];
  const float* W1 = (const float*)d_in[6];  const float* b1 = (const float*)d_in[7];
  const float* W2 = (const float*)d_in[8];  const float* b2 = (const float*)d_in[9];
  const float* Wc1 = (const float*)d_in[10]; const float* bc1 = (const float*)d_in[11];
  const float* Wc2 = (const float*)d_in[12]; const float* bc2 = (const float*)d_in[13];
  const int* srcp = ei;
  const int* dstp = ei + E;

  // ---- workspace carve-up (4-byte units) ----
  int* off    = (int*)d_ws;                      // N+2
  int* csrc   = off + N + 2;                     // E
  float* dinv = (float*)(csrc + E);              // N
  int* chist  = (int*)(dinv + N);                // 256
  int* cbase  = chist + 256;                     // 256 (B+1 used)
  int* gcur   = cbase + 256;                     // 256
  __half* xh  = (__half*)(gcur + 256);           // 4 slabs x N x 16 halfs (12.8MB)
  __half* y   = xh + (size_t)N * 64;             // N x 64 halfs (12.8MB)
  float* bufA = (float*)(y + (size_t)N * 64);    // N*64 fp32 (final agg out)
  int* ebuf   = (int*)bufA;                      // E ints (dead before agg2)
  float* hsum = bufA + (size_t)N * 64;           // G*64
  float* hmax = hsum + (size_t)G * 64;           // G*64
  int*   cntg = (int*)(hmax + (size_t)G * 64);   // G

  auto cdiv = [](long a, long b) { return (int)((a + b - 1) / b); };
  const int aggBlocks = 4 * cdiv(N, 16);   // blockIdx&3 = slab -> XCD affine

  // ---- CSR build (single-writer placement, packed ebuf) ----
  hipMemsetAsync(chist, 0, 256 * sizeof(int), stream);
  k_chist<<<cdiv(E, CHUNK), 256, 0, stream>>>(dstp, chist, E, B);
  k_cscan<<<1, 256, 0, stream>>>(chist, cbase, gcur, E, B);
  k_part<<<cdiv(E, CHUNK), 256, 0, stream>>>(srcp, dstp, gcur, ebuf, E, B);
  k_bplace<<<B, 512, 0, stream>>>(ebuf, cbase, off, csrc, dinv, N, E);

  // ---- 3 GCN layers ----
  k_matmul<true><<<cdiv(N, 256), 256, 0, stream>>>(nullptr, tok, emb, W0, dinv, (__half2*)xh, N);
  k_aggregate<true><<<aggBlocks, 256, 0, stream>>>(off, csrc, dinv, xh, b0, y, N);

  k_matmul<false><<<cdiv(N, 256), 256, 0, stream>>>(y, nullptr, nullptr, W1, dinv, (__half2*)xh, N);
  k_aggregate<true><<<aggBlocks, 256, 0, stream>>>(off, csrc, dinv, xh, b1, y, N);

  k_matmul<false><<<cdiv(N, 256), 256, 0, stream>>>(y, nullptr, nullptr, W2, dinv, (__half2*)xh, N);
  k_aggregate<false><<<aggBlocks, 256, 0, stream>>>(off, csrc, dinv, xh, nullptr, bufA, N);

  // ---- pooling (relu+b2 fused) ----
  hipMemsetAsync(hsum, 0, (size_t)G * 129 * sizeof(float), stream);
  k_pool<<<cdiv(N, 256), 256, 0, stream>>>(bufA, b2, batch, hsum, hmax, cntg, N);

  // ---- classifier head ----
  k_cls<<<G, 64, 0, stream>>>(hsum, hmax, cntg, Wc1, bc1, Wc2, bc2, (float*)d_out);
}

// Round 10
// 416.622 us; speedup vs baseline: 1.1430x; 1.1225x over previous
//
#include <hip/hip_runtime.h>
#include <hip/hip_fp16.h>
#include <math.h>

// ---------------------------------------------------------------------------
// DevignLite: 3-layer GCN + mean/max pool + MLP head.  N=100000, E=1.6M,
// D=64, G=256.
// Round 10:
//  - Aggregate: per-lane divergent edge loop (masked-off lanes issue NO
//    memory segments; no wave-max shuffles, no cndmask masks).
//  - Matmul -> MFMA 16x16x32_f16: W pre-packed to B-frag layout (k_wcvt),
//    emb pre-converted to fp16 y0 (k_embcvt).  Kills the 1024-broadcast-
//    VMEM-per-wave bottleneck of the pk_fma matmul.
//  - k_part: 2-pass, CHUNK 4096 (4x bigger single-writer slices).
// ---------------------------------------------------------------------------

#define BKT_LOG 9
#define BKT (1 << BKT_LOG)
#define CHUNK 4096

typedef _Float16 h2 __attribute__((ext_vector_type(2)));
typedef _Float16 f16x8 __attribute__((ext_vector_type(8)));
typedef float f32x4 __attribute__((ext_vector_type(4)));

union HU { unsigned u; h2 h; };
__device__ inline h2 h2bits(unsigned u) { HU x; x.u = u; return x.h; }

#if __has_builtin(__builtin_amdgcn_fdot2)
#define FDOT2(a, b, c) __builtin_amdgcn_fdot2((a), (b), (c), false)
#else
__device__ inline float FDOT2(h2 a, h2 b, float c) {
  return (float)a.x * (float)b.x + (float)a.y * (float)b.y + c;
}
#endif

#define MASK_X 0x00003C00u   // half2 (1,0)
#define MASK_Y 0x3C000000u   // half2 (0,1)

// acc[0..7] += convert of 8 halfs in v (via fdot2 with unit masks)
__device__ inline void acc8c(const uint4& v, float* acc) {
  const unsigned* w = (const unsigned*)&v;
#pragma unroll
  for (int k = 0; k < 4; k++) {
    h2 hv = h2bits(w[k]);
    acc[2 * k]     = FDOT2(hv, h2bits(MASK_X), acc[2 * k]);
    acc[2 * k + 1] = FDOT2(hv, h2bits(MASK_Y), acc[2 * k + 1]);
  }
}

// coarse histogram of dst >> BKT_LOG
__global__ __launch_bounds__(256) void k_chist(const int* __restrict__ dst,
                                               int* __restrict__ chist, int E, int B) {
  __shared__ int h[256];
  h[threadIdx.x] = 0;
  __syncthreads();
  for (long e = (long)blockIdx.x * blockDim.x + threadIdx.x; e < E;
       e += (long)gridDim.x * blockDim.x)
    atomicAdd(&h[dst[e] >> BKT_LOG], 1);
  __syncthreads();
  if (threadIdx.x < B && h[threadIdx.x]) atomicAdd(&chist[threadIdx.x], h[threadIdx.x]);
}

// exclusive scan of chist[B] -> cbase[B+1]; cursor copy -> gcur
__global__ __launch_bounds__(256) void k_cscan(const int* __restrict__ chist,
                                               int* __restrict__ cbase,
                                               int* __restrict__ gcur, int E, int B) {
  __shared__ int s[256];
  int v = (threadIdx.x < B) ? chist[threadIdx.x] : 0;
  s[threadIdx.x] = v;
  __syncthreads();
  for (int d = 1; d < 256; d <<= 1) {
    int t = (threadIdx.x >= (unsigned)d) ? s[threadIdx.x - d] : 0;
    __syncthreads();
    s[threadIdx.x] += t;
    __syncthreads();
  }
  if (threadIdx.x < B) {
    int ex = s[threadIdx.x] - v;
    cbase[threadIdx.x] = ex;
    gcur[threadIdx.x] = ex;
  }
  if (threadIdx.x == B) cbase[B] = E;
}

// partition: scatter packed (local_dst<<17 | src) into coarse-bucket order.
// 2-pass (re-read instead of register staging); CHUNK=4096 -> big slices.
__global__ __launch_bounds__(256) void k_part(const int* __restrict__ src,
                                              const int* __restrict__ dst,
                                              int* __restrict__ gcur,
                                              int* __restrict__ ebuf, int E, int B) {
  __shared__ int h[256], base[256];
  int tid = threadIdx.x;
  long c0 = (long)blockIdx.x * CHUNK;
  int m = (int)min((long)CHUNK, (long)E - c0);
  h[tid] = 0;
  __syncthreads();
  for (int i = tid; i < m; i += 256) atomicAdd(&h[dst[c0 + i] >> BKT_LOG], 1);
  __syncthreads();
  if (tid < B && h[tid]) base[tid] = atomicAdd(&gcur[tid], h[tid]);
  __syncthreads();
  h[tid] = 0;   // reuse as per-bucket cursor
  __syncthreads();
  for (int i = tid; i < m; i += 256) {
    int s = src[c0 + i];
    int d = dst[c0 + i];
    int k = d >> BKT_LOG;
    int p = base[k] + atomicAdd(&h[k], 1);
    ebuf[p] = ((d & (BKT - 1)) << 17) | s;
  }
}

// per-bucket: node histogram + scan in LDS -> off/dinv, then place csrc.
__global__ __launch_bounds__(512) void k_bplace(const int* __restrict__ ebuf,
                                                const int* __restrict__ cbase,
                                                int* __restrict__ off,
                                                int* __restrict__ csrc,
                                                float* __restrict__ dinv,
                                                int N, int E) {
  __shared__ int s[512];
  __shared__ int cur[512];
  int b = blockIdx.x, tid = threadIdx.x;
  int n0 = b << BKT_LOG;
  int nn = min(BKT, N - n0);
  int e0 = cbase[b], e1 = cbase[b + 1];
  s[tid] = 0;
  __syncthreads();
  for (int e = e0 + tid; e < e1; e += 512) atomicAdd(&s[ebuf[e] >> 17], 1);
  __syncthreads();
  int deg = s[tid];
  for (int d = 1; d < 512; d <<= 1) {
    int t = (tid >= d) ? s[tid - d] : 0;
    __syncthreads();
    s[tid] += t;
    __syncthreads();
  }
  int excl = s[tid] - deg;
  if (tid < nn) {
    off[n0 + tid] = e0 + excl;
    dinv[n0 + tid] = 1.0f / sqrtf((float)(1 + deg));
  }
  cur[tid] = excl;
  __syncthreads();
  for (int e = e0 + tid; e < e1; e += 512) {
    int p = ebuf[e];
    int pos = e0 + atomicAdd(&cur[p >> 17], 1);
    csrc[pos] = p & 0x1FFFF;
  }
  if (b == 0 && tid == 0) off[N] = E;
}

// W (fp32 [64][64] row-major, x@W convention) -> fp16 B-fragment layout:
// Wf[c*1024 + s*512 + l*8 + j] = W[(32s + 8*(l>>4) + j)*64 + 16c + (l&15)]
__global__ __launch_bounds__(256) void k_wcvt(const float* __restrict__ W0,
                                              const float* __restrict__ W1,
                                              const float* __restrict__ W2,
                                              _Float16* __restrict__ Wf) {
  const float* W = (blockIdx.x == 0) ? W0 : (blockIdx.x == 1) ? W1 : W2;
  _Float16* out = Wf + blockIdx.x * 4096;
  for (int i = threadIdx.x; i < 4096; i += 256) {
    int c = i >> 10, s = (i >> 9) & 1, l = (i >> 3) & 63, j = i & 7;
    int k = 32 * s + 8 * (l >> 4) + j;
    int ncol = 16 * c + (l & 15);
    out[i] = (_Float16)W[k * 64 + ncol];
  }
}

// y0[row][0..63] = fp16(emb[tok[row]][0..63]); thread = 8 feats
__global__ __launch_bounds__(256) void k_embcvt(const int* __restrict__ tok,
                                                const float* __restrict__ emb,
                                                _Float16* __restrict__ y, int n) {
  long t = (long)blockIdx.x * blockDim.x + threadIdx.x;
  int row = (int)(t >> 3), c8 = (int)(t & 7);
  if (row >= n) return;
  const float4* e4 = (const float4*)(emb + (size_t)tok[row] * 64 + c8 * 8);
  float4 v0 = e4[0], v1 = e4[1];
  _Float16 h[8] = {(_Float16)v0.x, (_Float16)v0.y, (_Float16)v0.z, (_Float16)v0.w,
                   (_Float16)v1.x, (_Float16)v1.y, (_Float16)v1.z, (_Float16)v1.w};
  *(uint4*)(y + (size_t)row * 64 + c8 * 8) = *(const uint4*)h;
}

// ---------------------------------------------------------------------------
// MFMA matmul: xh[slab c][node][16] = fp16( (y[node] @ W) * dinv[node]*scale )
// Block = 64 rows (4 waves x 16).  Per wave: 2 A-frags, 8 B-frags, 8 MFMA,
// LDS transpose epilogue -> coalesced 32B-row stores into slab layout.
// ---------------------------------------------------------------------------
__global__ __launch_bounds__(256) void k_mfmamm(const _Float16* __restrict__ y,
                                                const _Float16* __restrict__ Wf,
                                                const float* __restrict__ dinv,
                                                float scale,
                                                _Float16* __restrict__ xh,
                                                int n, int npad) {
  __shared__ _Float16 lds[4 * 16 * 72];
  int w = threadIdx.x >> 6, l = threadIdx.x & 63;
  int m = l & 15, q = l >> 4;
  int rbase = blockIdx.x * 64 + w * 16;

  const _Float16* yr = y + (size_t)(rbase + m) * 64;
  f16x8 a0 = *(const f16x8*)(yr + q * 8);
  f16x8 a1 = *(const f16x8*)(yr + 32 + q * 8);
  float4 d4 = *(const float4*)(dinv + rbase + q * 4);

  const f16x8* wf = (const f16x8*)Wf + l;
  f32x4 acc[4];
#pragma unroll
  for (int c = 0; c < 4; c++) {
    f32x4 z = {0.f, 0.f, 0.f, 0.f};
    z = __builtin_amdgcn_mfma_f32_16x16x32_f16(a0, wf[(c * 2 + 0) * 64], z, 0, 0, 0);
    z = __builtin_amdgcn_mfma_f32_16x16x32_f16(a1, wf[(c * 2 + 1) * 64], z, 0, 0, 0);
    acc[c] = z;
  }

  const float ds[4] = {d4.x * scale, d4.y * scale, d4.z * scale, d4.w * scale};
  _Float16* ldw = lds + w * 16 * 72;
#pragma unroll
  for (int c = 0; c < 4; c++)
#pragma unroll
    for (int r = 0; r < 4; r++)
      ldw[(q * 4 + r) * 72 + c * 16 + m] = (_Float16)(acc[c][r] * ds[r]);
  __syncthreads();

  int row2 = l & 15, c2 = l >> 4;
  int node = rbase + row2;
  if (node < n) {
    const uint4* s4 = (const uint4*)(ldw + row2 * 72 + c2 * 16);
    uint4 v0 = s4[0], v1 = s4[1];
    uint4* dst = (uint4*)(xh + ((size_t)c2 * npad + node) * 16);
    dst[0] = v0;
    dst[1] = v1;
  }
}

// ---------------------------------------------------------------------------
// Aggregate, slab-parallel, XCD-affine, per-lane divergent edge loop.
// chunk c = blockIdx&3; wave = 4 nodes; lane = (n4:bits4-5, g:bits1-3, o:bit0)
// FOLD: out = fp16 4096*relu(conv + bias)  (row-major [n][64])
// PLAIN: out = fp32 conv                   (row-major [n][64])
// conv = (dinv[t]/256) * (xh_c[t] + sum_in xh_c[s]).
// ---------------------------------------------------------------------------
template <bool FOLD>
__global__ __launch_bounds__(256) void k_aggregate(const int* __restrict__ off,
                                                   const int* __restrict__ csrc,
                                                   const float* __restrict__ dinv,
                                                   const _Float16* __restrict__ xh,
                                                   const float* __restrict__ bias,
                                                   void* __restrict__ outp,
                                                   int n, int npad) {
  int c = blockIdx.x & 3;
  int lane = threadIdx.x & 63;
  int n4 = lane >> 4, g = (lane >> 1) & 7, o = lane & 1;
  int t = (blockIdx.x >> 2) * 16 + (threadIdx.x >> 6) * 4 + n4;
  bool valid = t < n;
  int tc = valid ? t : n - 1;
  int e0 = off[tc], e1 = off[tc + 1];
  if (!valid) e1 = e0;
  const uint4* x4 = (const uint4*)xh + (size_t)c * npad * 2;   // 32B rows

  float acc[8];
#pragma unroll
  for (int k = 0; k < 8; k++) acc[k] = 0.f;
  if (g == 0) acc8c(x4[(size_t)tc * 2 + o], acc);   // self term

  for (int it = e0 + g; it < e1; it += 8) {          // divergent; masked lanes
    int s = csrc[it];                                // issue no segments
    uint4 v = x4[(size_t)s * 2 + o];
    acc8c(v, acc);
  }

  // reduce over g (lane bits 1-3)
#pragma unroll
  for (int mm = 2; mm <= 8; mm <<= 1) {
#pragma unroll
    for (int k = 0; k < 8; k++) acc[k] += __shfl_xor(acc[k], mm);
  }

  if (valid && g == 0) {
    float sc = dinv[t] * (1.0f / 256.0f);
    int f0 = c * 16 + o * 8;
    if (FOLD) {
      float4 bb0 = *(const float4*)(bias + f0);
      float4 bb1 = *(const float4*)(bias + f0 + 4);
      const float bs[8] = {bb0.x, bb0.y, bb0.z, bb0.w, bb1.x, bb1.y, bb1.z, bb1.w};
      _Float16 hh[8];
#pragma unroll
      for (int k = 0; k < 8; k++)
        hh[k] = (_Float16)(fmaxf(acc[k] * sc + bs[k], 0.f) * 4096.f);
      *(uint4*)((_Float16*)outp + (size_t)t * 64 + f0) = *(const uint4*)hh;
    } else {
      float4* p = (float4*)((float*)outp + (size_t)t * 64 + f0);
      p[0] = make_float4(acc[0] * sc, acc[1] * sc, acc[2] * sc, acc[3] * sc);
      p[1] = make_float4(acc[4] * sc, acc[5] * sc, acc[6] * sc, acc[7] * sc);
    }
  }
}

// batch is sorted: per-wave register segment reduction, flush on boundary.
__global__ __launch_bounds__(256) void k_pool(const float* __restrict__ x,
                                              const float* __restrict__ b,
                                              const int* __restrict__ batch,
                                              float* __restrict__ hsum,
                                              float* __restrict__ hmax,
                                              int* __restrict__ cntg, int n) {
  int wid = (blockIdx.x * blockDim.x + threadIdx.x) >> 6;
  int lane = threadIdx.x & 63;
  int i0 = wid * 64;
  if (i0 >= n) return;
  int i1 = min(i0 + 64, n);
  float bb = b[lane];
  int batch_l = (i0 + lane < n) ? batch[i0 + lane] : 0;
  float gsum = 0.f, gmax = 0.f;
  int cur = __shfl(batch_l, 0);
  int c = 0;
  for (int i = i0; i < i1; i++) {
    int g = __shfl(batch_l, i - i0);
    if (g != cur) {
      atomicAdd(&hsum[cur * 64 + lane], gsum);
      atomicMax((int*)&hmax[cur * 64 + lane], __float_as_int(gmax));
      if (lane == 0) atomicAdd(&cntg[cur], c);
      gsum = 0.f; gmax = 0.f; c = 0; cur = g;
    }
    float v = fmaxf(x[(long)i * 64 + lane] + bb, 0.0f);
    gsum += v;
    gmax = fmaxf(gmax, v);
    c++;
  }
  atomicAdd(&hsum[cur * 64 + lane], gsum);
  atomicMax((int*)&hmax[cur * 64 + lane], __float_as_int(gmax));
  if (lane == 0) atomicAdd(&cntg[cur], c);
}

// one block (64 threads) per graph: logits = relu(h@Wc1+bc1)@Wc2+bc2
__global__ __launch_bounds__(64) void k_cls(const float* __restrict__ hsum,
                                            const float* __restrict__ hmax,
                                            const int* __restrict__ cnt,
                                            const float* __restrict__ Wc1,
                                            const float* __restrict__ bc1,
                                            const float* __restrict__ Wc2,
                                            const float* __restrict__ bc2,
                                            float* __restrict__ out) {
  __shared__ float h[128];
  __shared__ float hid[64];
  int g = blockIdx.x, j = threadIdx.x;
  int c = cnt[g];
  float cf = (float)(c > 0 ? c : 1);
  h[j] = hsum[g * 64 + j] / cf;
  h[64 + j] = hmax[g * 64 + j];
  __syncthreads();
  float acc = bc1[j];
  for (int k = 0; k < 128; k++) acc += h[k] * Wc1[k * 64 + j];
  hid[j] = fmaxf(acc, 0.f);
  __syncthreads();
  if (j < 2) {
    float a = bc2[j];
    for (int k = 0; k < 64; k++) a += hid[k] * Wc2[k * 2 + j];
    out[g * 2 + j] = a;
  }
}

extern "C" void kernel_launch(void* const* d_in, const int* in_sizes, int n_in,
                              void* d_out, int out_size, void* d_ws, size_t ws_size,
                              hipStream_t stream) {
  const int N = in_sizes[0];
  const int E = in_sizes[1] / 2;
  const int G = out_size / 2;
  const int B = (N + BKT - 1) >> BKT_LOG;
  const int Npad = (N + 63) & ~63;

  const int* tok   = (const int*)d_in[0];
  const int* ei    = (const int*)d_in[1];
  const int* batch = (const int*)d_in[2];
  const float* emb = (const float*)d_in[3];
  const float* W0 = (const float*)d_in[4];  const float* b0 = (const float*)d_in[5];
  const float* W1 = (const float*)d_in[6];  const float* b1 = (const float*)d_in[7];
  const float* W2 = (const float*)d_in[8];  const float* b2 = (const float*)d_in[9];
  const float* Wc1 = (const float*)d_in[10]; const float* bc1 = (const float*)d_in[11];
  const float* Wc2 = (const float*)d_in[12]; const float* bc2 = (const float*)d_in[13];
  const int* srcp = ei;
  const int* dstp = ei + E;

  // ---- workspace carve-up (4-byte units) ----
  int* off    = (int*)d_ws;                      // N+2
  int* csrc   = off + N + 2;                     // E
  float* dinv = (float*)(csrc + E);              // Npad
  int* chist  = (int*)(dinv + Npad);             // 256
  int* cbase  = chist + 256;                     // 256 (B+1 used)
  int* gcur   = cbase + 256;                     // 256
  _Float16* Wf = (_Float16*)(gcur + 256);        // 3*4096 halfs (24 KB)
  _Float16* xh = Wf + 3 * 4096;                  // 4 slabs x Npad x 16 halfs
  _Float16* y  = xh + (size_t)Npad * 64;         // Npad x 64 halfs
  float* bufA = (float*)(y + (size_t)Npad * 64); // N*64 fp32 (final agg out)
  int* ebuf   = (int*)bufA;                      // E ints (dead before agg2)
  float* hsum = bufA + (size_t)N * 64;           // G*64
  float* hmax = hsum + (size_t)G * 64;           // G*64
  int*   cntg = (int*)(hmax + (size_t)G * 64);   // G

  auto cdiv = [](long a, long b) { return (int)((a + b - 1) / b); };
  const int aggBlocks = 4 * cdiv(N, 16);   // blockIdx&3 = slab -> XCD affine

  // ---- CSR build ----
  hipMemsetAsync(chist, 0, 256 * sizeof(int), stream);
  k_chist<<<cdiv(E, CHUNK), 256, 0, stream>>>(dstp, chist, E, B);
  k_cscan<<<1, 256, 0, stream>>>(chist, cbase, gcur, E, B);
  k_part<<<cdiv(E, CHUNK), 256, 0, stream>>>(srcp, dstp, gcur, ebuf, E, B);
  k_bplace<<<B, 512, 0, stream>>>(ebuf, cbase, off, csrc, dinv, N, E);

  // ---- weight + embedding conversion ----
  k_wcvt<<<3, 256, 0, stream>>>(W0, W1, W2, Wf);
  k_embcvt<<<cdiv((long)N * 8, 256), 256, 0, stream>>>(tok, emb, y, N);

  // ---- 3 GCN layers ----
  k_mfmamm<<<cdiv(N, 64), 256, 0, stream>>>(y, Wf, dinv, 256.f, xh, N, Npad);
  k_aggregate<true><<<aggBlocks, 256, 0, stream>>>(off, csrc, dinv, xh, b0, y, N, Npad);

  k_mfmamm<<<cdiv(N, 64), 256, 0, stream>>>(y, Wf + 4096, dinv, 1.f / 16.f, xh, N, Npad);
  k_aggregate<true><<<aggBlocks, 256, 0, stream>>>(off, csrc, dinv, xh, b1, y, N, Npad);

  k_mfmamm<<<cdiv(N, 64), 256, 0, stream>>>(y, Wf + 8192, dinv, 1.f / 16.f, xh, N, Npad);
  k_aggregate<false><<<aggBlocks, 256, 0, stream>>>(off, csrc, dinv, xh, nullptr, bufA, N, Npad);

  // ---- pooling (relu+b2 fused) ----
  hipMemsetAsync(hsum, 0, (size_t)G * 129 * sizeof(float), stream);
  k_pool<<<cdiv(N, 256), 256, 0, stream>>>(bufA, b2, batch, hsum, hmax, cntg, N);

  // ---- classifier head ----
  k_cls<<<G, 64, 0, stream>>>(hsum, hmax, cntg, Wc1, bc1, Wc2, bc2, (float*)d_out);
}

// Round 11
// 401.145 us; speedup vs baseline: 1.1871x; 1.0386x over previous
//
#include <hip/hip_runtime.h>
#include <hip/hip_fp16.h>
#include <math.h>

// ---------------------------------------------------------------------------
// DevignLite: 3-layer GCN + mean/max pool + MLP head.  N=100000, E=1.6M,
// D=64, G=256.
// Round 11:
//  - embcvt fused into k_mfmamm<EMB> (A-frag gathers emb rows inline).
//  - All 3 aggregates output fp16 4096*relu(conv+bias); pool reads fp16,
//    cls rescales by 1/4096.  (r10: fp32 agg tail cost 25.6MB W + 25.6MB R.)
//  - Aggregate: csrc prefetched one trip ahead -> per-trip chain is gather
//    latency only.
// ---------------------------------------------------------------------------

#define BKT_LOG 9
#define BKT (1 << BKT_LOG)
#define CHUNK 4096

typedef _Float16 h2 __attribute__((ext_vector_type(2)));
typedef _Float16 f16x8 __attribute__((ext_vector_type(8)));
typedef float f32x4 __attribute__((ext_vector_type(4)));

union HU { unsigned u; h2 h; };
__device__ inline h2 h2bits(unsigned u) { HU x; x.u = u; return x.h; }

#if __has_builtin(__builtin_amdgcn_fdot2)
#define FDOT2(a, b, c) __builtin_amdgcn_fdot2((a), (b), (c), false)
#else
__device__ inline float FDOT2(h2 a, h2 b, float c) {
  return (float)a.x * (float)b.x + (float)a.y * (float)b.y + c;
}
#endif

#define MASK_X 0x00003C00u   // half2 (1,0)
#define MASK_Y 0x3C000000u   // half2 (0,1)

// acc[0..7] += convert of 8 halfs in v (via fdot2 with unit masks)
__device__ inline void acc8c(const uint4& v, float* acc) {
  const unsigned* w = (const unsigned*)&v;
#pragma unroll
  for (int k = 0; k < 4; k++) {
    h2 hv = h2bits(w[k]);
    acc[2 * k]     = FDOT2(hv, h2bits(MASK_X), acc[2 * k]);
    acc[2 * k + 1] = FDOT2(hv, h2bits(MASK_Y), acc[2 * k + 1]);
  }
}

// coarse histogram of dst >> BKT_LOG
__global__ __launch_bounds__(256) void k_chist(const int* __restrict__ dst,
                                               int* __restrict__ chist, int E, int B) {
  __shared__ int h[256];
  h[threadIdx.x] = 0;
  __syncthreads();
  for (long e = (long)blockIdx.x * blockDim.x + threadIdx.x; e < E;
       e += (long)gridDim.x * blockDim.x)
    atomicAdd(&h[dst[e] >> BKT_LOG], 1);
  __syncthreads();
  if (threadIdx.x < B && h[threadIdx.x]) atomicAdd(&chist[threadIdx.x], h[threadIdx.x]);
}

// exclusive scan of chist[B] -> cbase[B+1]; cursor copy -> gcur
__global__ __launch_bounds__(256) void k_cscan(const int* __restrict__ chist,
                                               int* __restrict__ cbase,
                                               int* __restrict__ gcur, int E, int B) {
  __shared__ int s[256];
  int v = (threadIdx.x < B) ? chist[threadIdx.x] : 0;
  s[threadIdx.x] = v;
  __syncthreads();
  for (int d = 1; d < 256; d <<= 1) {
    int t = (threadIdx.x >= (unsigned)d) ? s[threadIdx.x - d] : 0;
    __syncthreads();
    s[threadIdx.x] += t;
    __syncthreads();
  }
  if (threadIdx.x < B) {
    int ex = s[threadIdx.x] - v;
    cbase[threadIdx.x] = ex;
    gcur[threadIdx.x] = ex;
  }
  if (threadIdx.x == B) cbase[B] = E;
}

// partition: scatter packed (local_dst<<17 | src) into coarse-bucket order.
__global__ __launch_bounds__(256) void k_part(const int* __restrict__ src,
                                              const int* __restrict__ dst,
                                              int* __restrict__ gcur,
                                              int* __restrict__ ebuf, int E, int B) {
  __shared__ int h[256], base[256];
  int tid = threadIdx.x;
  long c0 = (long)blockIdx.x * CHUNK;
  int m = (int)min((long)CHUNK, (long)E - c0);
  h[tid] = 0;
  __syncthreads();
  for (int i = tid; i < m; i += 256) atomicAdd(&h[dst[c0 + i] >> BKT_LOG], 1);
  __syncthreads();
  if (tid < B && h[tid]) base[tid] = atomicAdd(&gcur[tid], h[tid]);
  __syncthreads();
  h[tid] = 0;   // reuse as per-bucket cursor
  __syncthreads();
  for (int i = tid; i < m; i += 256) {
    int s = src[c0 + i];
    int d = dst[c0 + i];
    int k = d >> BKT_LOG;
    int p = base[k] + atomicAdd(&h[k], 1);
    ebuf[p] = ((d & (BKT - 1)) << 17) | s;
  }
}

// per-bucket: node histogram + scan in LDS -> off/dinv, then place csrc.
__global__ __launch_bounds__(512) void k_bplace(const int* __restrict__ ebuf,
                                                const int* __restrict__ cbase,
                                                int* __restrict__ off,
                                                int* __restrict__ csrc,
                                                float* __restrict__ dinv,
                                                int N, int E) {
  __shared__ int s[512];
  __shared__ int cur[512];
  int b = blockIdx.x, tid = threadIdx.x;
  int n0 = b << BKT_LOG;
  int nn = min(BKT, N - n0);
  int e0 = cbase[b], e1 = cbase[b + 1];
  s[tid] = 0;
  __syncthreads();
  for (int e = e0 + tid; e < e1; e += 512) atomicAdd(&s[ebuf[e] >> 17], 1);
  __syncthreads();
  int deg = s[tid];
  for (int d = 1; d < 512; d <<= 1) {
    int t = (tid >= d) ? s[tid - d] : 0;
    __syncthreads();
    s[tid] += t;
    __syncthreads();
  }
  int excl = s[tid] - deg;
  if (tid < nn) {
    off[n0 + tid] = e0 + excl;
    dinv[n0 + tid] = 1.0f / sqrtf((float)(1 + deg));
  }
  cur[tid] = excl;
  __syncthreads();
  for (int e = e0 + tid; e < e1; e += 512) {
    int p = ebuf[e];
    int pos = e0 + atomicAdd(&cur[p >> 17], 1);
    csrc[pos] = p & 0x1FFFF;
  }
  if (b == 0 && tid == 0) off[N] = E;
}

// W (fp32 [64][64] row-major, x@W convention) -> fp16 B-fragment layout.
__global__ __launch_bounds__(256) void k_wcvt(const float* __restrict__ W0,
                                              const float* __restrict__ W1,
                                              const float* __restrict__ W2,
                                              _Float16* __restrict__ Wf) {
  const float* W = (blockIdx.x == 0) ? W0 : (blockIdx.x == 1) ? W1 : W2;
  _Float16* out = Wf + blockIdx.x * 4096;
  for (int i = threadIdx.x; i < 4096; i += 256) {
    int c = i >> 10, s = (i >> 9) & 1, l = (i >> 3) & 63, j = i & 7;
    int k = 32 * s + 8 * (l >> 4) + j;
    int ncol = 16 * c + (l & 15);
    out[i] = (_Float16)W[k * 64 + ncol];
  }
}

// ---------------------------------------------------------------------------
// MFMA matmul: xh[slab c][node][16] = fp16( (in[node] @ W) * dinv[node]*scale )
// EMB: in = fp32 emb rows gathered by tok (converted inline); else fp16 y.
// Block = 64 rows (4 waves x 16); per wave 2 A-frags, 8 B-frags, 8 MFMA,
// LDS transpose epilogue -> coalesced 32B-row stores into slab layout.
// ---------------------------------------------------------------------------
template <bool EMB>
__global__ __launch_bounds__(256) void k_mfmamm(const _Float16* __restrict__ y,
                                                const int* __restrict__ tok,
                                                const float* __restrict__ emb,
                                                const _Float16* __restrict__ Wf,
                                                const float* __restrict__ dinv,
                                                float scale,
                                                _Float16* __restrict__ xh,
                                                int n, int npad) {
  __shared__ _Float16 lds[4 * 16 * 72];
  int w = threadIdx.x >> 6, l = threadIdx.x & 63;
  int m = l & 15, q = l >> 4;
  int rbase = blockIdx.x * 64 + w * 16;

  f16x8 a0, a1;
  if (EMB) {
    int node = min(rbase + m, n - 1);
    const float* er = emb + (size_t)tok[node] * 64;
    float4 v0 = *(const float4*)(er + q * 8);
    float4 v1 = *(const float4*)(er + q * 8 + 4);
    float4 v2 = *(const float4*)(er + 32 + q * 8);
    float4 v3 = *(const float4*)(er + 32 + q * 8 + 4);
    a0[0] = (_Float16)v0.x; a0[1] = (_Float16)v0.y; a0[2] = (_Float16)v0.z; a0[3] = (_Float16)v0.w;
    a0[4] = (_Float16)v1.x; a0[5] = (_Float16)v1.y; a0[6] = (_Float16)v1.z; a0[7] = (_Float16)v1.w;
    a1[0] = (_Float16)v2.x; a1[1] = (_Float16)v2.y; a1[2] = (_Float16)v2.z; a1[3] = (_Float16)v2.w;
    a1[4] = (_Float16)v3.x; a1[5] = (_Float16)v3.y; a1[6] = (_Float16)v3.z; a1[7] = (_Float16)v3.w;
  } else {
    const _Float16* yr = y + (size_t)(rbase + m) * 64;
    a0 = *(const f16x8*)(yr + q * 8);
    a1 = *(const f16x8*)(yr + 32 + q * 8);
  }
  float4 d4 = *(const float4*)(dinv + rbase + q * 4);

  const f16x8* wf = (const f16x8*)Wf + l;
  f32x4 acc[4];
#pragma unroll
  for (int c = 0; c < 4; c++) {
    f32x4 z = {0.f, 0.f, 0.f, 0.f};
    z = __builtin_amdgcn_mfma_f32_16x16x32_f16(a0, wf[(c * 2 + 0) * 64], z, 0, 0, 0);
    z = __builtin_amdgcn_mfma_f32_16x16x32_f16(a1, wf[(c * 2 + 1) * 64], z, 0, 0, 0);
    acc[c] = z;
  }

  const float ds[4] = {d4.x * scale, d4.y * scale, d4.z * scale, d4.w * scale};
  _Float16* ldw = lds + w * 16 * 72;
#pragma unroll
  for (int c = 0; c < 4; c++)
#pragma unroll
    for (int r = 0; r < 4; r++)
      ldw[(q * 4 + r) * 72 + c * 16 + m] = (_Float16)(acc[c][r] * ds[r]);
  __syncthreads();

  int row2 = l & 15, c2 = l >> 4;
  int node = rbase + row2;
  if (node < n) {
    const uint4* s4 = (const uint4*)(ldw + row2 * 72 + c2 * 16);
    uint4 v0 = s4[0], v1 = s4[1];
    uint4* dst = (uint4*)(xh + ((size_t)c2 * npad + node) * 16);
    dst[0] = v0;
    dst[1] = v1;
  }
}

// ---------------------------------------------------------------------------
// Aggregate, slab-parallel, XCD-affine, index-prefetch pipeline.
// chunk c = blockIdx&3; wave = 4 nodes; lane = (n4:bits4-5, g:bits1-3, o:bit0)
// out = fp16 4096*relu(conv + bias)  (row-major [n][64])
// conv = (dinv[t]/256) * (xh_c[t] + sum_in xh_c[s]).
// ---------------------------------------------------------------------------
__global__ __launch_bounds__(256) void k_aggregate(const int* __restrict__ off,
                                                   const int* __restrict__ csrc,
                                                   const float* __restrict__ dinv,
                                                   const _Float16* __restrict__ xh,
                                                   const float* __restrict__ bias,
                                                   _Float16* __restrict__ outp,
                                                   int n, int npad) {
  int c = blockIdx.x & 3;
  int lane = threadIdx.x & 63;
  int n4 = lane >> 4, g = (lane >> 1) & 7, o = lane & 1;
  int t = (blockIdx.x >> 2) * 16 + (threadIdx.x >> 6) * 4 + n4;
  bool valid = t < n;
  int tc = valid ? t : n - 1;
  int e0 = off[tc], e1 = off[tc + 1];
  if (!valid) e1 = e0;
  const uint4* x4 = (const uint4*)xh + (size_t)c * npad * 2;   // 32B rows

  float acc[8];
#pragma unroll
  for (int k = 0; k < 8; k++) acc[k] = 0.f;
  if (g == 0) acc8c(x4[(size_t)tc * 2 + o], acc);   // self term

  int it = e0 + g;
  int s = (it < e1) ? csrc[it] : 0;                  // pipelined index
  while (it < e1) {
    int itn = it + 8;
    int sn = (itn < e1) ? csrc[itn] : 0;             // prefetch next index
    uint4 v = x4[(size_t)s * 2 + o];                 // gather current row
    acc8c(v, acc);
    s = sn;
    it = itn;
  }

  // reduce over g (lane bits 1-3)
#pragma unroll
  for (int mm = 2; mm <= 8; mm <<= 1) {
#pragma unroll
    for (int k = 0; k < 8; k++) acc[k] += __shfl_xor(acc[k], mm);
  }

  if (valid && g == 0) {
    float sc = dinv[t] * (1.0f / 256.0f);
    int f0 = c * 16 + o * 8;
    float4 bb0 = *(const float4*)(bias + f0);
    float4 bb1 = *(const float4*)(bias + f0 + 4);
    const float bs[8] = {bb0.x, bb0.y, bb0.z, bb0.w, bb1.x, bb1.y, bb1.z, bb1.w};
    _Float16 hh[8];
#pragma unroll
    for (int k = 0; k < 8; k++)
      hh[k] = (_Float16)(fmaxf(acc[k] * sc + bs[k], 0.f) * 4096.f);
    *(uint4*)(outp + (size_t)t * 64 + f0) = *(const uint4*)hh;
  }
}

// batch is sorted: per-wave register segment reduction over fp16 y (x4096).
__global__ __launch_bounds__(256) void k_pool(const _Float16* __restrict__ x,
                                              const int* __restrict__ batch,
                                              float* __restrict__ hsum,
                                              float* __restrict__ hmax,
                                              int* __restrict__ cntg, int n) {
  int wid = (blockIdx.x * blockDim.x + threadIdx.x) >> 6;
  int lane = threadIdx.x & 63;
  int i0 = wid * 64;
  if (i0 >= n) return;
  int i1 = min(i0 + 64, n);
  int batch_l = (i0 + lane < n) ? batch[i0 + lane] : 0;
  float gsum = 0.f, gmax = 0.f;
  int cur = __shfl(batch_l, 0);
  int c = 0;
  for (int i = i0; i < i1; i++) {
    int g = __shfl(batch_l, i - i0);
    if (g != cur) {
      atomicAdd(&hsum[cur * 64 + lane], gsum);
      atomicMax((int*)&hmax[cur * 64 + lane], __float_as_int(gmax));
      if (lane == 0) atomicAdd(&cntg[cur], c);
      gsum = 0.f; gmax = 0.f; c = 0; cur = g;
    }
    float v = (float)x[(long)i * 64 + lane];   // relu+bias already folded
    gsum += v;
    gmax = fmaxf(gmax, v);
    c++;
  }
  atomicAdd(&hsum[cur * 64 + lane], gsum);
  atomicMax((int*)&hmax[cur * 64 + lane], __float_as_int(gmax));
  if (lane == 0) atomicAdd(&cntg[cur], c);
}

// one block (64 threads) per graph: logits = relu(h@Wc1+bc1)@Wc2+bc2
// hsum/hmax carry the 4096x scale; undone here.
__global__ __launch_bounds__(64) void k_cls(const float* __restrict__ hsum,
                                            const float* __restrict__ hmax,
                                            const int* __restrict__ cnt,
                                            const float* __restrict__ Wc1,
                                            const float* __restrict__ bc1,
                                            const float* __restrict__ Wc2,
                                            const float* __restrict__ bc2,
                                            float* __restrict__ out) {
  __shared__ float h[128];
  __shared__ float hid[64];
  int g = blockIdx.x, j = threadIdx.x;
  int c = cnt[g];
  float cf = (float)(c > 0 ? c : 1);
  h[j] = hsum[g * 64 + j] / cf * (1.0f / 4096.0f);
  h[64 + j] = hmax[g * 64 + j] * (1.0f / 4096.0f);
  __syncthreads();
  float acc = bc1[j];
  for (int k = 0; k < 128; k++) acc += h[k] * Wc1[k * 64 + j];
  hid[j] = fmaxf(acc, 0.f);
  __syncthreads();
  if (j < 2) {
    float a = bc2[j];
    for (int k = 0; k < 64; k++) a += hid[k] * Wc2[k * 2 + j];
    out[g * 2 + j] = a;
  }
}

extern "C" void kernel_launch(void* const* d_in, const int* in_sizes, int n_in,
                              void* d_out, int out_size, void* d_ws, size_t ws_size,
                              hipStream_t stream) {
  const int N = in_sizes[0];
  const int E = in_sizes[1] / 2;
  const int G = out_size / 2;
  const int B = (N + BKT - 1) >> BKT_LOG;
  const int Npad = (N + 63) & ~63;

  const int* tok   = (const int*)d_in[0];
  const int* ei    = (const int*)d_in[1];
  const int* batch = (const int*)d_in[2];
  const float* emb = (const float*)d_in[3];
  const float* W0 = (const float*)d_in[4];  const float* b0 = (const float*)d_in[5];
  const float* W1 = (const float*)d_in[6];  const float* b1 = (const float*)d_in[7];
  const float* W2 = (const float*)d_in[8];  const float* b2 = (const float*)d_in[9];
  const float* Wc1 = (const float*)d_in[10]; const float* bc1 = (const float*)d_in[11];
  const float* Wc2 = (const float*)d_in[12]; const float* bc2 = (const float*)d_in[13];
  const int* srcp = ei;
  const int* dstp = ei + E;

  // ---- workspace carve-up (4-byte units) ----
  int* off    = (int*)d_ws;                      // N+2
  int* csrc   = off + N + 2;                     // E
  float* dinv = (float*)(csrc + E);              // Npad
  int* chist  = (int*)(dinv + Npad);             // 256
  int* cbase  = chist + 256;                     // 256 (B+1 used)
  int* gcur   = cbase + 256;                     // 256
  _Float16* Wf = (_Float16*)(gcur + 256);        // 3*4096 halfs
  _Float16* xh = Wf + 3 * 4096;                  // 4 slabs x Npad x 16 halfs
  _Float16* y  = xh + (size_t)Npad * 64;         // Npad x 64 halfs
  int* ebuf   = (int*)(y + (size_t)Npad * 64);   // E ints (dead after bplace)
  float* hsum = (float*)(ebuf + E);              // G*64
  float* hmax = hsum + (size_t)G * 64;           // G*64
  int*   cntg = (int*)(hmax + (size_t)G * 64);   // G

  auto cdiv = [](long a, long b) { return (int)((a + b - 1) / b); };
  const int aggBlocks = 4 * cdiv(N, 16);   // blockIdx&3 = slab -> XCD affine

  // ---- CSR build ----
  hipMemsetAsync(chist, 0, 256 * sizeof(int), stream);
  k_chist<<<cdiv(E, CHUNK), 256, 0, stream>>>(dstp, chist, E, B);
  k_cscan<<<1, 256, 0, stream>>>(chist, cbase, gcur, E, B);
  k_part<<<cdiv(E, CHUNK), 256, 0, stream>>>(srcp, dstp, gcur, ebuf, E, B);
  k_bplace<<<B, 512, 0, stream>>>(ebuf, cbase, off, csrc, dinv, N, E);

  // ---- weight conversion ----
  k_wcvt<<<3, 256, 0, stream>>>(W0, W1, W2, Wf);

  // ---- 3 GCN layers ----
  k_mfmamm<true><<<cdiv(N, 64), 256, 0, stream>>>(nullptr, tok, emb, Wf, dinv, 256.f, xh, N, Npad);
  k_aggregate<<<aggBlocks, 256, 0, stream>>>(off, csrc, dinv, xh, b0, y, N, Npad);

  k_mfmamm<false><<<cdiv(N, 64), 256, 0, stream>>>(y, nullptr, nullptr, Wf + 4096, dinv, 1.f / 16.f, xh, N, Npad);
  k_aggregate<<<aggBlocks, 256, 0, stream>>>(off, csrc, dinv, xh, b1, y, N, Npad);

  k_mfmamm<false><<<cdiv(N, 64), 256, 0, stream>>>(y, nullptr, nullptr, Wf + 8192, dinv, 1.f / 16.f, xh, N, Npad);
  k_aggregate<<<aggBlocks, 256, 0, stream>>>(off, csrc, dinv, xh, b2, y, N, Npad);

  // ---- pooling ----
  hipMemsetAsync(hsum, 0, (size_t)G * 129 * sizeof(float), stream);
  k_pool<<<cdiv(N, 256), 256, 0, stream>>>(y, batch, hsum, hmax, cntg, N);

  // ---- classifier head ----
  k_cls<<<G, 64, 0, stream>>>(hsum, hmax, cntg, Wc1, bc1, Wc2, bc2, (float*)d_out);
}

// Round 12
// 371.817 us; speedup vs baseline: 1.2808x; 1.0789x over previous
//
#include <hip/hip_runtime.h>
#include <hip/hip_fp16.h>
#include <math.h>

// ---------------------------------------------------------------------------
// DevignLite: 3-layer GCN + mean/max pool + MLP head.  N=100000, E=1.6M,
// D=64, G=256.
// Round 12:
//  - y (inter-layer activations) stored SLAB-MAJOR [c][Npad][16] like xh:
//    aggregate writes become single-writer full-line (r11 counter: WRITE
//    25MB for a 12.8MB output = 4-XCD quarter-line false sharing).
//  - k_part stages its chunk in LDS (reads src/dst once, not dst twice).
//  - memsets folded into k_wcvt (blocks 3-4) -> 13 dispatches total.
// ---------------------------------------------------------------------------

#define BKT_LOG 9
#define BKT (1 << BKT_LOG)
#define CHUNK 4096

typedef _Float16 h2 __attribute__((ext_vector_type(2)));
typedef _Float16 f16x8 __attribute__((ext_vector_type(8)));
typedef float f32x4 __attribute__((ext_vector_type(4)));

union HU { unsigned u; h2 h; };
__device__ inline h2 h2bits(unsigned u) { HU x; x.u = u; return x.h; }

#if __has_builtin(__builtin_amdgcn_fdot2)
#define FDOT2(a, b, c) __builtin_amdgcn_fdot2((a), (b), (c), false)
#else
__device__ inline float FDOT2(h2 a, h2 b, float c) {
  return (float)a.x * (float)b.x + (float)a.y * (float)b.y + c;
}
#endif

#define MASK_X 0x00003C00u   // half2 (1,0)
#define MASK_Y 0x3C000000u   // half2 (0,1)

// acc[0..7] += convert of 8 halfs in v (via fdot2 with unit masks)
__device__ inline void acc8c(const uint4& v, float* acc) {
  const unsigned* w = (const unsigned*)&v;
#pragma unroll
  for (int k = 0; k < 4; k++) {
    h2 hv = h2bits(w[k]);
    acc[2 * k]     = FDOT2(hv, h2bits(MASK_X), acc[2 * k]);
    acc[2 * k + 1] = FDOT2(hv, h2bits(MASK_Y), acc[2 * k + 1]);
  }
}

// W conversion to fp16 B-frag layout (blocks 0-2) + workspace zeroing
// (block 3: chist, block 4: hsum/hmax/cntg).  Launched first.
__global__ __launch_bounds__(256) void k_wcvt(const float* __restrict__ W0,
                                              const float* __restrict__ W1,
                                              const float* __restrict__ W2,
                                              _Float16* __restrict__ Wf,
                                              int* __restrict__ chist,
                                              float* __restrict__ hz, int hzn) {
  if (blockIdx.x < 3) {
    const float* W = (blockIdx.x == 0) ? W0 : (blockIdx.x == 1) ? W1 : W2;
    _Float16* out = Wf + blockIdx.x * 4096;
    for (int i = threadIdx.x; i < 4096; i += 256) {
      int c = i >> 10, s = (i >> 9) & 1, l = (i >> 3) & 63, j = i & 7;
      int k = 32 * s + 8 * (l >> 4) + j;
      int ncol = 16 * c + (l & 15);
      out[i] = (_Float16)W[k * 64 + ncol];
    }
  } else if (blockIdx.x == 3) {
    chist[threadIdx.x] = 0;
  } else {
    for (int i = threadIdx.x; i < hzn; i += 256) hz[i] = 0.f;
  }
}

// coarse histogram of dst >> BKT_LOG
__global__ __launch_bounds__(256) void k_chist(const int* __restrict__ dst,
                                               int* __restrict__ chist, int E, int B) {
  __shared__ int h[256];
  h[threadIdx.x] = 0;
  __syncthreads();
  for (long e = (long)blockIdx.x * blockDim.x + threadIdx.x; e < E;
       e += (long)gridDim.x * blockDim.x)
    atomicAdd(&h[dst[e] >> BKT_LOG], 1);
  __syncthreads();
  if (threadIdx.x < B && h[threadIdx.x]) atomicAdd(&chist[threadIdx.x], h[threadIdx.x]);
}

// exclusive scan of chist[B] -> cbase[B+1]; cursor copy -> gcur
__global__ __launch_bounds__(256) void k_cscan(const int* __restrict__ chist,
                                               int* __restrict__ cbase,
                                               int* __restrict__ gcur, int E, int B) {
  __shared__ int s[256];
  int v = (threadIdx.x < B) ? chist[threadIdx.x] : 0;
  s[threadIdx.x] = v;
  __syncthreads();
  for (int d = 1; d < 256; d <<= 1) {
    int t = (threadIdx.x >= (unsigned)d) ? s[threadIdx.x - d] : 0;
    __syncthreads();
    s[threadIdx.x] += t;
    __syncthreads();
  }
  if (threadIdx.x < B) {
    int ex = s[threadIdx.x] - v;
    cbase[threadIdx.x] = ex;
    gcur[threadIdx.x] = ex;
  }
  if (threadIdx.x == B) cbase[B] = E;
}

// partition: scatter packed (local_dst<<17 | src) into coarse-bucket order.
// LDS-staged: src/dst read exactly once from HBM.
__global__ __launch_bounds__(256) void k_part(const int* __restrict__ src,
                                              const int* __restrict__ dst,
                                              int* __restrict__ gcur,
                                              int* __restrict__ ebuf, int E, int B) {
  __shared__ int sA[CHUNK];
  __shared__ int dA[CHUNK];
  __shared__ int h[256], base[256];
  int tid = threadIdx.x;
  long c0 = (long)blockIdx.x * CHUNK;
  int m = (int)min((long)CHUNK, (long)E - c0);
  h[tid] = 0;
  __syncthreads();
  for (int i = tid; i < m; i += 256) {
    int s = src[c0 + i];
    int d = dst[c0 + i];
    sA[i] = s;
    dA[i] = d;
    atomicAdd(&h[d >> BKT_LOG], 1);
  }
  __syncthreads();
  if (tid < B && h[tid]) base[tid] = atomicAdd(&gcur[tid], h[tid]);
  __syncthreads();
  h[tid] = 0;   // reuse as per-bucket cursor
  __syncthreads();
  for (int i = tid; i < m; i += 256) {
    int s = sA[i], d = dA[i];
    int k = d >> BKT_LOG;
    int p = base[k] + atomicAdd(&h[k], 1);
    ebuf[p] = ((d & (BKT - 1)) << 17) | s;
  }
}

// per-bucket: node histogram + scan in LDS -> off/dinv, then place csrc.
__global__ __launch_bounds__(512) void k_bplace(const int* __restrict__ ebuf,
                                                const int* __restrict__ cbase,
                                                int* __restrict__ off,
                                                int* __restrict__ csrc,
                                                float* __restrict__ dinv,
                                                int N, int E) {
  __shared__ int s[512];
  __shared__ int cur[512];
  int b = blockIdx.x, tid = threadIdx.x;
  int n0 = b << BKT_LOG;
  int nn = min(BKT, N - n0);
  int e0 = cbase[b], e1 = cbase[b + 1];
  s[tid] = 0;
  __syncthreads();
  for (int e = e0 + tid; e < e1; e += 512) atomicAdd(&s[ebuf[e] >> 17], 1);
  __syncthreads();
  int deg = s[tid];
  for (int d = 1; d < 512; d <<= 1) {
    int t = (tid >= d) ? s[tid - d] : 0;
    __syncthreads();
    s[tid] += t;
    __syncthreads();
  }
  int excl = s[tid] - deg;
  if (tid < nn) {
    off[n0 + tid] = e0 + excl;
    dinv[n0 + tid] = 1.0f / sqrtf((float)(1 + deg));
  }
  cur[tid] = excl;
  __syncthreads();
  for (int e = e0 + tid; e < e1; e += 512) {
    int p = ebuf[e];
    int pos = e0 + atomicAdd(&cur[p >> 17], 1);
    csrc[pos] = p & 0x1FFFF;
  }
  if (b == 0 && tid == 0) off[N] = E;
}

// ---------------------------------------------------------------------------
// MFMA matmul: xh[c][node][16] = fp16( (in[node] @ W) * dinv[node]*scale )
// EMB: in = fp32 emb rows gathered by tok; else fp16 y in slab-major layout.
// ---------------------------------------------------------------------------
template <bool EMB>
__global__ __launch_bounds__(256) void k_mfmamm(const _Float16* __restrict__ y,
                                                const int* __restrict__ tok,
                                                const float* __restrict__ emb,
                                                const _Float16* __restrict__ Wf,
                                                const float* __restrict__ dinv,
                                                float scale,
                                                _Float16* __restrict__ xh,
                                                int n, int npad) {
  __shared__ _Float16 lds[4 * 16 * 72];
  int w = threadIdx.x >> 6, l = threadIdx.x & 63;
  int m = l & 15, q = l >> 4;
  int rbase = blockIdx.x * 64 + w * 16;

  f16x8 a0, a1;
  if (EMB) {
    int node = min(rbase + m, n - 1);
    const float* er = emb + (size_t)tok[node] * 64;
    float4 v0 = *(const float4*)(er + q * 8);
    float4 v1 = *(const float4*)(er + q * 8 + 4);
    float4 v2 = *(const float4*)(er + 32 + q * 8);
    float4 v3 = *(const float4*)(er + 32 + q * 8 + 4);
    a0[0] = (_Float16)v0.x; a0[1] = (_Float16)v0.y; a0[2] = (_Float16)v0.z; a0[3] = (_Float16)v0.w;
    a0[4] = (_Float16)v1.x; a0[5] = (_Float16)v1.y; a0[6] = (_Float16)v1.z; a0[7] = (_Float16)v1.w;
    a1[0] = (_Float16)v2.x; a1[1] = (_Float16)v2.y; a1[2] = (_Float16)v2.z; a1[3] = (_Float16)v2.w;
    a1[4] = (_Float16)v3.x; a1[5] = (_Float16)v3.y; a1[6] = (_Float16)v3.z; a1[7] = (_Float16)v3.w;
  } else {
    int node = rbase + m;
    // slab-major y: feat f lives at y[(f>>4)*npad*16 + node*16 + (f&15)]
    a0 = *(const f16x8*)(y + ((size_t)(q >> 1) * npad + node) * 16 + (q & 1) * 8);
    a1 = *(const f16x8*)(y + ((size_t)((q >> 1) + 2) * npad + node) * 16 + (q & 1) * 8);
  }
  float4 d4 = *(const float4*)(dinv + rbase + q * 4);

  const f16x8* wf = (const f16x8*)Wf + l;
  f32x4 acc[4];
#pragma unroll
  for (int c = 0; c < 4; c++) {
    f32x4 z = {0.f, 0.f, 0.f, 0.f};
    z = __builtin_amdgcn_mfma_f32_16x16x32_f16(a0, wf[(c * 2 + 0) * 64], z, 0, 0, 0);
    z = __builtin_amdgcn_mfma_f32_16x16x32_f16(a1, wf[(c * 2 + 1) * 64], z, 0, 0, 0);
    acc[c] = z;
  }

  const float ds[4] = {d4.x * scale, d4.y * scale, d4.z * scale, d4.w * scale};
  _Float16* ldw = lds + w * 16 * 72;
#pragma unroll
  for (int c = 0; c < 4; c++)
#pragma unroll
    for (int r = 0; r < 4; r++)
      ldw[(q * 4 + r) * 72 + c * 16 + m] = (_Float16)(acc[c][r] * ds[r]);
  __syncthreads();

  int row2 = l & 15, c2 = l >> 4;
  int node = rbase + row2;
  if (node < n) {
    const uint4* s4 = (const uint4*)(ldw + row2 * 72 + c2 * 16);
    uint4 v0 = s4[0], v1 = s4[1];
    uint4* dst = (uint4*)(xh + ((size_t)c2 * npad + node) * 16);
    dst[0] = v0;
    dst[1] = v1;
  }
}

// ---------------------------------------------------------------------------
// Aggregate, slab-parallel, XCD-affine, index-prefetch pipeline.
// chunk c = blockIdx&3; wave = 4 nodes; lane = (n4:bits4-5, g:bits1-3, o:bit0)
// out (slab-major [c][npad][16]) = fp16 4096*relu(conv + bias)
// conv = (dinv[t]/256) * (xh_c[t] + sum_in xh_c[s]).
// ---------------------------------------------------------------------------
__global__ __launch_bounds__(256) void k_aggregate(const int* __restrict__ off,
                                                   const int* __restrict__ csrc,
                                                   const float* __restrict__ dinv,
                                                   const _Float16* __restrict__ xh,
                                                   const float* __restrict__ bias,
                                                   _Float16* __restrict__ outp,
                                                   int n, int npad) {
  int c = blockIdx.x & 3;
  int lane = threadIdx.x & 63;
  int n4 = lane >> 4, g = (lane >> 1) & 7, o = lane & 1;
  int t = (blockIdx.x >> 2) * 16 + (threadIdx.x >> 6) * 4 + n4;
  bool valid = t < n;
  int tc = valid ? t : n - 1;
  int e0 = off[tc], e1 = off[tc + 1];
  if (!valid) e1 = e0;
  const uint4* x4 = (const uint4*)xh + (size_t)c * npad * 2;   // 32B rows

  float acc[8];
#pragma unroll
  for (int k = 0; k < 8; k++) acc[k] = 0.f;
  if (g == 0) acc8c(x4[(size_t)tc * 2 + o], acc);   // self term

  int it = e0 + g;
  int s = (it < e1) ? csrc[it] : 0;                  // pipelined index
  while (it < e1) {
    int itn = it + 8;
    int sn = (itn < e1) ? csrc[itn] : 0;             // prefetch next index
    uint4 v = x4[(size_t)s * 2 + o];                 // gather current row
    acc8c(v, acc);
    s = sn;
    it = itn;
  }

  // reduce over g (lane bits 1-3)
#pragma unroll
  for (int mm = 2; mm <= 8; mm <<= 1) {
#pragma unroll
    for (int k = 0; k < 8; k++) acc[k] += __shfl_xor(acc[k], mm);
  }

  if (valid && g == 0) {
    float sc = dinv[t] * (1.0f / 256.0f);
    int f0 = c * 16 + o * 8;
    float4 bb0 = *(const float4*)(bias + f0);
    float4 bb1 = *(const float4*)(bias + f0 + 4);
    const float bs[8] = {bb0.x, bb0.y, bb0.z, bb0.w, bb1.x, bb1.y, bb1.z, bb1.w};
    _Float16 hh[8];
#pragma unroll
    for (int k = 0; k < 8; k++)
      hh[k] = (_Float16)(fmaxf(acc[k] * sc + bs[k], 0.f) * 4096.f);
    // slab-major store: single-writer full lines (wave covers t..t+3 x 32B)
    *(uint4*)(outp + ((size_t)c * npad + t) * 16 + o * 8) = *(const uint4*)hh;
  }
}

// batch is sorted: per-wave register segment reduction over slab-major fp16 y.
__global__ __launch_bounds__(256) void k_pool(const _Float16* __restrict__ x,
                                              const int* __restrict__ batch,
                                              float* __restrict__ hsum,
                                              float* __restrict__ hmax,
                                              int* __restrict__ cntg,
                                              int n, int npad) {
  int wid = (blockIdx.x * blockDim.x + threadIdx.x) >> 6;
  int lane = threadIdx.x & 63;
  int i0 = wid * 64;
  if (i0 >= n) return;
  int i1 = min(i0 + 64, n);
  size_t sb = (size_t)(lane >> 4) * npad * 16 + (lane & 15);
  int batch_l = (i0 + lane < n) ? batch[i0 + lane] : 0;
  float gsum = 0.f, gmax = 0.f;
  int cur = __shfl(batch_l, 0);
  int c = 0;
  for (int i = i0; i < i1; i++) {
    int g = __shfl(batch_l, i - i0);
    if (g != cur) {
      atomicAdd(&hsum[cur * 64 + lane], gsum);
      atomicMax((int*)&hmax[cur * 64 + lane], __float_as_int(gmax));
      if (lane == 0) atomicAdd(&cntg[cur], c);
      gsum = 0.f; gmax = 0.f; c = 0; cur = g;
    }
    float v = (float)x[sb + (size_t)i * 16];   // relu+bias already folded
    gsum += v;
    gmax = fmaxf(gmax, v);
    c++;
  }
  atomicAdd(&hsum[cur * 64 + lane], gsum);
  atomicMax((int*)&hmax[cur * 64 + lane], __float_as_int(gmax));
  if (lane == 0) atomicAdd(&cntg[cur], c);
}

// one block (64 threads) per graph: logits = relu(h@Wc1+bc1)@Wc2+bc2
// hsum/hmax carry the 4096x scale and feature order (lane->slab-feat);
// note pool's lane f maps feature (f>>4)*16+(f&15) == f.  Undo 4096 here.
__global__ __launch_bounds__(64) void k_cls(const float* __restrict__ hsum,
                                            const float* __restrict__ hmax,
                                            const int* __restrict__ cnt,
                                            const float* __restrict__ Wc1,
                                            const float* __restrict__ bc1,
                                            const float* __restrict__ Wc2,
                                            const float* __restrict__ bc2,
                                            float* __restrict__ out) {
  __shared__ float h[128];
  __shared__ float hid[64];
  int g = blockIdx.x, j = threadIdx.x;
  int c = cnt[g];
  float cf = (float)(c > 0 ? c : 1);
  h[j] = hsum[g * 64 + j] / cf * (1.0f / 4096.0f);
  h[64 + j] = hmax[g * 64 + j] * (1.0f / 4096.0f);
  __syncthreads();
  float acc = bc1[j];
  for (int k = 0; k < 128; k++) acc += h[k] * Wc1[k * 64 + j];
  hid[j] = fmaxf(acc, 0.f);
  __syncthreads();
  if (j < 2) {
    float a = bc2[j];
    for (int k = 0; k < 64; k++) a += hid[k] * Wc2[k * 2 + j];
    out[g * 2 + j] = a;
  }
}

extern "C" void kernel_launch(void* const* d_in, const int* in_sizes, int n_in,
                              void* d_out, int out_size, void* d_ws, size_t ws_size,
                              hipStream_t stream) {
  const int N = in_sizes[0];
  const int E = in_sizes[1] / 2;
  const int G = out_size / 2;
  const int B = (N + BKT - 1) >> BKT_LOG;
  const int Npad = (N + 63) & ~63;

  const int* tok   = (const int*)d_in[0];
  const int* ei    = (const int*)d_in[1];
  const int* batch = (const int*)d_in[2];
  const float* emb = (const float*)d_in[3];
  const float* W0 = (const float*)d_in[4];  const float* b0 = (const float*)d_in[5];
  const float* W1 = (const float*)d_in[6];  const float* b1 = (const float*)d_in[7];
  const float* W2 = (const float*)d_in[8];  const float* b2 = (const float*)d_in[9];
  const float* Wc1 = (const float*)d_in[10]; const float* bc1 = (const float*)d_in[11];
  const float* Wc2 = (const float*)d_in[12]; const float* bc2 = (const float*)d_in[13];
  const int* srcp = ei;
  const int* dstp = ei + E;

  // ---- workspace carve-up (4-byte units) ----
  int* off    = (int*)d_ws;                      // N+2
  int* csrc   = off + N + 2;                     // E
  float* dinv = (float*)(csrc + E);              // Npad
  int* chist  = (int*)(dinv + Npad);             // 256
  int* cbase  = chist + 256;                     // 256 (B+1 used)
  int* gcur   = cbase + 256;                     // 256
  _Float16* Wf = (_Float16*)(gcur + 256);        // 3*4096 halfs
  _Float16* xh = Wf + 3 * 4096;                  // 4 slabs x Npad x 16 halfs
  _Float16* y  = xh + (size_t)Npad * 64;         // 4 slabs x Npad x 16 halfs
  int* ebuf   = (int*)(y + (size_t)Npad * 64);   // E ints (dead after bplace)
  float* hsum = (float*)(ebuf + E);              // G*64
  float* hmax = hsum + (size_t)G * 64;           // G*64
  int*   cntg = (int*)(hmax + (size_t)G * 64);   // G

  auto cdiv = [](long a, long b) { return (int)((a + b - 1) / b); };
  const int aggBlocks = 4 * cdiv(N, 16);   // blockIdx&3 = slab -> XCD affine

  // ---- weight conversion + workspace zeroing (replaces 2 memsets) ----
  k_wcvt<<<5, 256, 0, stream>>>(W0, W1, W2, Wf, chist, hsum, G * 129);

  // ---- CSR build ----
  k_chist<<<cdiv(E, CHUNK), 256, 0, stream>>>(dstp, chist, E, B);
  k_cscan<<<1, 256, 0, stream>>>(chist, cbase, gcur, E, B);
  k_part<<<cdiv(E, CHUNK), 256, 0, stream>>>(srcp, dstp, gcur, ebuf, E, B);
  k_bplace<<<B, 512, 0, stream>>>(ebuf, cbase, off, csrc, dinv, N, E);

  // ---- 3 GCN layers ----
  k_mfmamm<true><<<cdiv(N, 64), 256, 0, stream>>>(nullptr, tok, emb, Wf, dinv, 256.f, xh, N, Npad);
  k_aggregate<<<aggBlocks, 256, 0, stream>>>(off, csrc, dinv, xh, b0, y, N, Npad);

  k_mfmamm<false><<<cdiv(N, 64), 256, 0, stream>>>(y, nullptr, nullptr, Wf + 4096, dinv, 1.f / 16.f, xh, N, Npad);
  k_aggregate<<<aggBlocks, 256, 0, stream>>>(off, csrc, dinv, xh, b1, y, N, Npad);

  k_mfmamm<false><<<cdiv(N, 64), 256, 0, stream>>>(y, nullptr, nullptr, Wf + 8192, dinv, 1.f / 16.f, xh, N, Npad);
  k_aggregate<<<aggBlocks, 256, 0, stream>>>(off, csrc, dinv, xh, b2, y, N, Npad);

  // ---- pooling ----
  k_pool<<<cdiv(N, 256), 256, 0, stream>>>(y, batch, hsum, hmax, cntg, N, Npad);

  // ---- classifier head ----
  k_cls<<<G, 64, 0, stream>>>(hsum, hmax, cntg, Wc1, bc1, Wc2, bc2, (float*)d_out);
}